// Round 1
// baseline (740.008 us; speedup 1.0000x reference)
//
#include <hip/hip_runtime.h>
#include <stdint.h>

typedef unsigned short u16;
typedef __attribute__((ext_vector_type(8))) __bf16 bf16x8;
typedef __attribute__((ext_vector_type(4))) float f32x4;

#define NREL 7
#define DIM  512
#define DEDGE 59
#define NHCOL 4096   // NREL*512 + 512 (self block appended)
#define KC   420     // NREL*59 + NREL (weight-sum columns)
#define KCP  448     // padded to multiple of 32 for MFMA K

__device__ __forceinline__ float bf2f(u16 u) {
  union { unsigned u; float f; } c; c.u = ((unsigned)u) << 16; return c.f;
}
__device__ __forceinline__ u16 f2bf(float f) {
  union { float f; unsigned u; } c; c.f = f;
  unsigned r = ((c.u >> 16) & 1u) + 0x7FFFu;
  return (u16)((c.u + r) >> 16);
}

__device__ __forceinline__ void gload16(const void* g, void* l) {
  __builtin_amdgcn_global_load_lds(
      (__attribute__((address_space(1))) void*)g,
      (__attribute__((address_space(3))) void*)l, 16, 0, 0);
}

// ---- convert node_feat fp32 -> bf16 (vectorized x4) ----
__global__ void convA(const float* __restrict__ in, u16* __restrict__ out, int total4) {
  int i = blockIdx.x * 256 + threadIdx.x;
  if (i >= total4) return;
  float4 v = ((const float4*)in)[i];
  ushort4 r;
  r.x = f2bf(v.x); r.y = f2bf(v.y); r.z = f2bf(v.z); r.w = f2bf(v.w);
  ((ushort4*)out)[i] = r;
}

// ---- build Bt[j][k] (bf16, [4096][512]): j<3584 -> W_lin[o, r*512+k]; else W_self[j-3584][k] ----
__global__ void buildBt(const float* __restrict__ W_lin, const float* __restrict__ W_self,
                        u16* __restrict__ Bt, int total4) {
  int gid = blockIdx.x * 256 + threadIdx.x;
  if (gid >= total4) return;
  int idx = gid * 4;
  int j = idx >> 9;
  int k = idx & 511;
  const float* src;
  if (j < NREL * DIM) {
    int r = j >> 9, o = j & 511;
    src = W_lin + (size_t)o * (NREL * DIM) + (size_t)r * DIM + k;
  } else {
    src = W_self + (size_t)(j - NREL * DIM) * DIM + k;
  }
  float4 v = *(const float4*)src;
  ushort4 rr;
  rr.x = f2bf(v.x); rr.y = f2bf(v.y); rr.z = f2bf(v.z); rr.w = f2bf(v.w);
  ((ushort4*)Bt)[gid] = rr;
}

// ---- build CxT[o][c] (bf16, [512][448]): c=r*59+de -> sum_d W_edge[d,de]*W_lin[o,r*512+d];
//      c=413+r -> sum_d b_edge[d]*W_lin[o,r*512+d]; c>=420 -> 0 ----
__global__ __launch_bounds__(512) void buildCx(const float* __restrict__ W_edge,
                                               const float* __restrict__ b_edge,
                                               const float* __restrict__ W_lin,
                                               u16* __restrict__ CxT) {
  int c = blockIdx.x;          // 0..447
  int o = threadIdx.x;         // 0..511
  if (c >= KC) { CxT[(size_t)o * KCP + c] = 0; return; }
  __shared__ float col[DIM];
  int r;
  if (c < NREL * DEDGE) {
    r = c / DEDGE;
    int de = c - r * DEDGE;
    col[o] = W_edge[(size_t)o * DEDGE + de];
  } else {
    r = c - NREL * DEDGE;
    col[o] = b_edge[o];
  }
  __syncthreads();
  const float* wrow = W_lin + (size_t)o * (NREL * DIM) + (size_t)r * DIM;
  float acc = 0.f;
#pragma unroll 8
  for (int d = 0; d < DIM; ++d) acc += col[d] * wrow[d];
  CxT[(size_t)o * KCP + c] = f2bf(acc);
}

// ---- scatter Gx[n][c] fp32: c<413: += w*ef[de] at c=rel*59+de; c=413+rel: += w ----
__global__ __launch_bounds__(256) void scatterG(const float* __restrict__ ef,
                                                const float* __restrict__ ew,
                                                const int* __restrict__ node_out,
                                                const int* __restrict__ relation,
                                                float* __restrict__ Gx, int E) {
  int e = blockIdx.x * 4 + (threadIdx.x >> 6);
  int lane = threadIdx.x & 63;
  if (e >= E) return;
  int n = node_out[e];
  int r = relation[e];
  float w = ew[e];
  float* row = Gx + (size_t)n * KC;
  if (lane < DEDGE) {
    atomicAdd(&row[r * DEDGE + lane], w * ef[(size_t)e * DEDGE + lane]);
  } else if (lane == DEDGE) {
    atomicAdd(&row[NREL * DEDGE + r], w);
  }
}

// ---- convert Gx fp32 [N][420] -> Gxb bf16 [N][448] padded ----
__global__ void convGx(const float* __restrict__ Gx, u16* __restrict__ Gxb, int N) {
  int gid = blockIdx.x * 256 + threadIdx.x;   // over N*112 (448/4)
  if (gid >= N * (KCP / 4)) return;
  int n = gid / (KCP / 4);
  int c4 = (gid - n * (KCP / 4)) * 4;
  ushort4 r4;
  if (c4 < KC) {
    float4 v = *(const float4*)(Gx + (size_t)n * KC + c4);
    r4.x = f2bf(v.x); r4.y = f2bf(v.y); r4.z = f2bf(v.z); r4.w = f2bf(v.w);
  } else {
    r4.x = r4.y = r4.z = r4.w = 0;
  }
  *(ushort4*)(Gxb + (size_t)n * KCP + c4) = r4;
}

// ---- CSR build ----
__global__ void countK(const int* __restrict__ node_out, int* __restrict__ counts, int E) {
  int e = blockIdx.x * 256 + threadIdx.x;
  if (e < E) atomicAdd(&counts[node_out[e]], 1);
}

__global__ __launch_bounds__(1024) void scanK(const int* __restrict__ counts,
                                              int* __restrict__ offs,
                                              int* __restrict__ cursor, int n) {
  __shared__ int lds[1024];
  int tid = threadIdx.x;
  int carry = 0;
  for (int base = 0; base < n; base += 1024) {
    int i = base + tid;
    int v = (i < n) ? counts[i] : 0;
    lds[tid] = v;
    __syncthreads();
    for (int o = 1; o < 1024; o <<= 1) {
      int t = (tid >= o) ? lds[tid - o] : 0;
      __syncthreads();
      lds[tid] += t;
      __syncthreads();
    }
    int excl = lds[tid] - v;
    if (i < n) { int val = carry + excl; offs[i] = val; cursor[i] = val; }
    int total = lds[1023];
    carry += total;
    __syncthreads();
  }
  if (tid == 0) offs[n] = carry;
}

__global__ void fillK(const int* __restrict__ node_out, int* __restrict__ cursor,
                      int* __restrict__ eids, int E) {
  int e = blockIdx.x * 256 + threadIdx.x;
  if (e < E) {
    int p = atomicAdd(&cursor[node_out[e]], 1);
    eids[p] = e;
  }
}

// ---- MFMA GEMM: C[M,Nn] = A[M,KS](bf16) * Bt[Nn,KS](bf16)^T ; 128x128 tile, BK=32 ----
template <int KS, bool OBF>
__global__ __launch_bounds__(256) void mfma_gemm(const u16* __restrict__ A,
                                                 const u16* __restrict__ Bt,
                                                 void* __restrict__ Cout, int M, int Nn) {
  __shared__ __align__(16) u16 sA[128 * 32];
  __shared__ __align__(16) u16 sB[128 * 32];
  const int tid = threadIdx.x;
  const int w = tid >> 6, l = tid & 63;
  const int lr = l & 15, kg = l >> 4;
  const int m0 = blockIdx.y * 128, n0 = blockIdx.x * 128;
  const int wr = w >> 1, wc = w & 1;
  f32x4 acc[4][4];
  const f32x4 z4 = {0.f, 0.f, 0.f, 0.f};
#pragma unroll
  for (int i = 0; i < 4; ++i)
#pragma unroll
    for (int j = 0; j < 4; ++j) acc[i][j] = z4;

  const int ktiles = KS / 32;
  for (int kt = 0; kt < ktiles; ++kt) {
    const int k0 = kt * 32;
#pragma unroll
    for (int t = 0; t < 2; ++t) {
      int idx = w * 128 + t * 64 + l;     // 16B chunk id within A tile
      int row = idx >> 2, kp = idx & 3;
      int gm = m0 + row; gm = gm < M ? gm : M - 1;
      gload16(A + (size_t)gm * KS + k0 + kp * 8,
              (char*)sA + (size_t)(w * 128 + t * 64) * 16);
    }
#pragma unroll
    for (int t = 0; t < 2; ++t) {
      int idx = w * 128 + t * 64 + l;
      int row = idx >> 2, kp = idx & 3;
      gload16(Bt + (size_t)(n0 + row) * KS + k0 + kp * 8,
              (char*)sB + (size_t)(w * 128 + t * 64) * 16);
    }
    __syncthreads();
    bf16x8 af[4], bfr[4];
#pragma unroll
    for (int i = 0; i < 4; ++i)
      af[i] = *(const bf16x8*)(sA + (size_t)(wr * 64 + i * 16 + lr) * 32 + kg * 8);
#pragma unroll
    for (int j = 0; j < 4; ++j)
      bfr[j] = *(const bf16x8*)(sB + (size_t)(wc * 64 + j * 16 + lr) * 32 + kg * 8);
#pragma unroll
    for (int i = 0; i < 4; ++i)
#pragma unroll
      for (int j = 0; j < 4; ++j)
        acc[i][j] = __builtin_amdgcn_mfma_f32_16x16x32_bf16(af[i], bfr[j], acc[i][j], 0, 0, 0);
    __syncthreads();
  }
  // epilogue: D col = lane&15, row = (lane>>4)*4 + v  [verified C/D layout]
#pragma unroll
  for (int i = 0; i < 4; ++i) {
#pragma unroll
    for (int j = 0; j < 4; ++j) {
      int gj = n0 + wc * 64 + j * 16 + lr;
#pragma unroll
      for (int v = 0; v < 4; ++v) {
        int gm = m0 + wr * 64 + i * 16 + kg * 4 + v;
        if (gm < M) {
          if constexpr (OBF) ((u16*)Cout)[(size_t)gm * Nn + gj] = f2bf(acc[i][j][v]);
          else               ((float*)Cout)[(size_t)gm * Nn + gj] = acc[i][j][v];
        }
      }
    }
  }
}

// ---- final gather-reduce: out[n,:] = relu(edgepath(out) + b_lin + b_self + H[n,self]
//                                           + sum_e w_e * H[src_e, rel_e, :]) ----
__global__ __launch_bounds__(128) void reduceKK(const u16* __restrict__ H,
                                                const float* __restrict__ ew,
                                                const int* __restrict__ node_in,
                                                const int* __restrict__ relation,
                                                const int* __restrict__ offs,
                                                const int* __restrict__ eids,
                                                const float* __restrict__ b_lin,
                                                const float* __restrict__ b_self,
                                                float* __restrict__ out) {
  int n = blockIdx.x;
  int o0 = threadIdx.x * 4;
  float4 b1 = *(const float4*)(b_lin + o0);
  float4 b2 = *(const float4*)(b_self + o0);
  float4 oi = *(const float4*)(out + (size_t)n * DIM + o0);
  ushort4 hs = *(const ushort4*)(H + (size_t)n * NHCOL + NREL * DIM + o0);
  float a0 = oi.x + b1.x + b2.x + bf2f(hs.x);
  float a1 = oi.y + b1.y + b2.y + bf2f(hs.y);
  float a2 = oi.z + b1.z + b2.z + bf2f(hs.z);
  float a3 = oi.w + b1.w + b2.w + bf2f(hs.w);
  int p0 = offs[n], p1 = offs[n + 1];
  for (int p = p0; p < p1; ++p) {
    int e = eids[p];
    float w = ew[e];
    int src = node_in[e];
    int rel = relation[e];
    ushort4 hv = *(const ushort4*)(H + (size_t)src * NHCOL + (size_t)rel * DIM + o0);
    a0 += w * bf2f(hv.x);
    a1 += w * bf2f(hv.y);
    a2 += w * bf2f(hv.z);
    a3 += w * bf2f(hv.w);
  }
  float4 r;
  r.x = fmaxf(a0, 0.f); r.y = fmaxf(a1, 0.f);
  r.z = fmaxf(a2, 0.f); r.w = fmaxf(a3, 0.f);
  *(float4*)(out + (size_t)n * DIM + o0) = r;
}

extern "C" void kernel_launch(void* const* d_in, const int* in_sizes, int n_in,
                              void* d_out, int out_size, void* d_ws, size_t ws_size,
                              hipStream_t stream) {
  const float* node_feat = (const float*)d_in[0];
  const float* edge_weight = (const float*)d_in[1];
  const float* edge_feat = (const float*)d_in[2];
  const float* W_lin = (const float*)d_in[3];
  const float* b_lin = (const float*)d_in[4];
  const float* W_self = (const float*)d_in[5];
  const float* b_self = (const float*)d_in[6];
  const float* W_edge = (const float*)d_in[7];
  const float* b_edge = (const float*)d_in[8];
  const int* node_in = (const int*)d_in[9];
  const int* node_out = (const int*)d_in[10];
  const int* relation = (const int*)d_in[11];
  float* out = (float*)d_out;

  const int N = in_sizes[0] / DIM;
  const int E = in_sizes[1];

  char* ws = (char*)d_ws;
  size_t off = 0;
  auto take = [&](size_t b) {
    char* p = ws + off;
    off += (b + 255) & ~(size_t)255;
    return p;
  };
  u16* Abf    = (u16*)take((size_t)N * DIM * 2);     // reused as Gxb after gemmH
  u16* Bt     = (u16*)take((size_t)NHCOL * DIM * 2);
  u16* H      = (u16*)take((size_t)N * NHCOL * 2);
  u16* CxT    = (u16*)take((size_t)DIM * KCP * 2);
  float* Gx   = (float*)take((size_t)N * KC * 4);
  int* counts = (int*)take((size_t)N * 4);
  int* offs   = (int*)take((size_t)(N + 1) * 4);
  int* cursor = (int*)take((size_t)N * 4);
  int* eids   = (int*)take((size_t)E * 4);
  if (off > ws_size) return;  // workspace too small — fail visibly via absmax

  u16* Gxb = Abf;  // reuse (N*KCP*2 <= N*DIM*2)

  hipMemsetAsync(Gx, 0, (size_t)N * KC * 4, stream);
  hipMemsetAsync(counts, 0, (size_t)N * 4, stream);

  {
    int total4 = N * DIM / 4;
    convA<<<(total4 + 255) / 256, 256, 0, stream>>>(node_feat, Abf, total4);
  }
  {
    int total4 = NHCOL * DIM / 4;
    buildBt<<<(total4 + 255) / 256, 256, 0, stream>>>(W_lin, W_self, Bt, total4);
  }
  buildCx<<<KCP, 512, 0, stream>>>(W_edge, b_edge, W_lin, CxT);
  scatterG<<<(E + 3) / 4, 256, 0, stream>>>(edge_feat, edge_weight, node_out, relation, Gx, E);
  countK<<<(E + 255) / 256, 256, 0, stream>>>(node_out, counts, E);
  scanK<<<1, 1024, 0, stream>>>(counts, offs, cursor, N);
  fillK<<<(E + 255) / 256, 256, 0, stream>>>(node_out, cursor, eids, E);

  // H[N, 4096] = Abf[N,512] @ Bt[4096,512]^T  (node path + self path)
  mfma_gemm<DIM, true><<<dim3(NHCOL / 128, (N + 127) / 128), 256, 0, stream>>>(
      Abf, Bt, (void*)H, N, NHCOL);

  // edge path: out[N,512] = Gxb[N,448] @ CxT[512,448]^T   (Abf dead now, reuse as Gxb)
  convGx<<<(N * (KCP / 4) + 255) / 256, 256, 0, stream>>>(Gx, Gxb, N);
  mfma_gemm<KCP, false><<<dim3(DIM / 128, (N + 127) / 128), 256, 0, stream>>>(
      Gxb, CxT, (void*)out, N, DIM);

  // final gather-reduce + biases + relu
  reduceKK<<<N, 128, 0, stream>>>(H, edge_weight, node_in, relation, offs, eids,
                                  b_lin, b_self, out);
}

// Round 2
// 627.932 us; speedup vs baseline: 1.1785x; 1.1785x over previous
//
#include <hip/hip_runtime.h>
#include <stdint.h>

typedef unsigned short u16;
typedef __attribute__((ext_vector_type(8))) __bf16 bf16x8;
typedef __attribute__((ext_vector_type(4))) float f32x4;

#define NREL 7
#define DIM  512
#define DEDGE 59
#define NHCOL 4096   // NREL*512 + 512 (self block appended)
#define KC   420     // NREL*59 + NREL (weight-sum columns)
#define KCP  448     // padded to multiple of 32 for MFMA K

__device__ __forceinline__ float bf2f(u16 u) {
  union { unsigned u; float f; } c; c.u = ((unsigned)u) << 16; return c.f;
}
__device__ __forceinline__ u16 f2bf(float f) {
  union { float f; unsigned u; } c; c.f = f;
  unsigned r = ((c.u >> 16) & 1u) + 0x7FFFu;
  return (u16)((c.u + r) >> 16);
}

__device__ __forceinline__ void gload16(const void* g, void* l) {
  __builtin_amdgcn_global_load_lds(
      (__attribute__((address_space(1))) void*)g,
      (__attribute__((address_space(3))) void*)l, 16, 0, 0);
}

// ---- convert node_feat fp32 -> bf16 (vectorized x4) ----
__global__ void convA(const float* __restrict__ in, u16* __restrict__ out, int total4) {
  int i = blockIdx.x * 256 + threadIdx.x;
  if (i >= total4) return;
  float4 v = ((const float4*)in)[i];
  ushort4 r;
  r.x = f2bf(v.x); r.y = f2bf(v.y); r.z = f2bf(v.z); r.w = f2bf(v.w);
  ((ushort4*)out)[i] = r;
}

// ---- build Bt[j][k] (bf16, [4096][512]): j<3584 -> W_lin[o, r*512+k]; else W_self[j-3584][k] ----
__global__ void buildBt(const float* __restrict__ W_lin, const float* __restrict__ W_self,
                        u16* __restrict__ Bt, int total4) {
  int gid = blockIdx.x * 256 + threadIdx.x;
  if (gid >= total4) return;
  int idx = gid * 4;
  int j = idx >> 9;
  int k = idx & 511;
  const float* src;
  if (j < NREL * DIM) {
    int r = j >> 9, o = j & 511;
    src = W_lin + (size_t)o * (NREL * DIM) + (size_t)r * DIM + k;
  } else {
    src = W_self + (size_t)(j - NREL * DIM) * DIM + k;
  }
  float4 v = *(const float4*)src;
  ushort4 rr;
  rr.x = f2bf(v.x); rr.y = f2bf(v.y); rr.z = f2bf(v.z); rr.w = f2bf(v.w);
  ((ushort4*)Bt)[gid] = rr;
}

// ---- build CxT[o][c] (bf16, [512][448]): c=r*59+de -> sum_d W_edge[d,de]*W_lin[o,r*512+d];
//      c=413+r -> sum_d b_edge[d]*W_lin[o,r*512+d]; c>=420 -> 0 ----
__global__ __launch_bounds__(512) void buildCx(const float* __restrict__ W_edge,
                                               const float* __restrict__ b_edge,
                                               const float* __restrict__ W_lin,
                                               u16* __restrict__ CxT) {
  int c = blockIdx.x;          // 0..447
  int o = threadIdx.x;         // 0..511
  if (c >= KC) { CxT[(size_t)o * KCP + c] = 0; return; }
  __shared__ float col[DIM];
  int r;
  if (c < NREL * DEDGE) {
    r = c / DEDGE;
    int de = c - r * DEDGE;
    col[o] = W_edge[(size_t)o * DEDGE + de];
  } else {
    r = c - NREL * DEDGE;
    col[o] = b_edge[o];
  }
  __syncthreads();
  const float* wrow = W_lin + (size_t)o * (NREL * DIM) + (size_t)r * DIM;
  float acc = 0.f;
#pragma unroll 8
  for (int d = 0; d < DIM; ++d) acc += col[d] * wrow[d];
  CxT[(size_t)o * KCP + c] = f2bf(acc);
}

// ---- CSR build (by node_out) ----
__global__ void countK(const int* __restrict__ node_out, int* __restrict__ counts, int E) {
  int e = blockIdx.x * 256 + threadIdx.x;
  if (e < E) atomicAdd(&counts[node_out[e]], 1);
}

__global__ __launch_bounds__(1024) void scanK(const int* __restrict__ counts,
                                              int* __restrict__ offs,
                                              int* __restrict__ cursor, int n) {
  __shared__ int lds[1024];
  int tid = threadIdx.x;
  int carry = 0;
  for (int base = 0; base < n; base += 1024) {
    int i = base + tid;
    int v = (i < n) ? counts[i] : 0;
    lds[tid] = v;
    __syncthreads();
    for (int o = 1; o < 1024; o <<= 1) {
      int t = (tid >= o) ? lds[tid - o] : 0;
      __syncthreads();
      lds[tid] += t;
      __syncthreads();
    }
    int excl = lds[tid] - v;
    if (i < n) { int val = carry + excl; offs[i] = val; cursor[i] = val; }
    int total = lds[1023];
    carry += total;
    __syncthreads();
  }
  if (tid == 0) offs[n] = carry;
}

__global__ void fillK(const int* __restrict__ node_out, int* __restrict__ cursor,
                      int* __restrict__ eids, int E) {
  int e = blockIdx.x * 256 + threadIdx.x;
  if (e < E) {
    int p = atomicAdd(&cursor[node_out[e]], 1);
    eids[p] = e;
  }
}

// ---- atomic-free edge aggregation via CSR: one wave per node.
// Gxb[n][c] bf16 (KCP=448 padded): c=r*59+de -> sum_{e: out=n, rel=r} w_e*ef[e][de]
//                                  c=413+r   -> sum w_e ; c in [420,448) -> 0
// Per-relation accumulators live in 7 registers per lane (compile-time unrolled
// predicated FMA — avoids runtime reg indexing -> scratch).
__global__ __launch_bounds__(64) void gatherG(const float* __restrict__ ef,
                                              const float* __restrict__ ew,
                                              const int* __restrict__ relation,
                                              const int* __restrict__ offs,
                                              const int* __restrict__ eids,
                                              u16* __restrict__ Gxb) {
  int n = blockIdx.x;
  int lane = threadIdx.x;
  float acc[NREL];
#pragma unroll
  for (int r = 0; r < NREL; ++r) acc[r] = 0.f;
  int p0 = offs[n], p1 = offs[n + 1];
  for (int p = p0; p < p1; ++p) {
    int e = __builtin_amdgcn_readfirstlane(eids[p]);
    float w = ew[e];
    int rel = relation[e];
    float v = (lane < DEDGE) ? ef[(size_t)e * DEDGE + lane] : 1.0f;
    float wv = w * v;
#pragma unroll
    for (int r = 0; r < NREL; ++r) acc[r] += (rel == r) ? wv : 0.f;
  }
  u16* row = Gxb + (size_t)n * KCP;
  if (lane < DEDGE) {
#pragma unroll
    for (int r = 0; r < NREL; ++r) row[r * DEDGE + lane] = f2bf(acc[r]);
  } else if (lane == DEDGE) {
#pragma unroll
    for (int r = 0; r < NREL; ++r) row[NREL * DEDGE + r] = f2bf(acc[r]);
  } else {
    // zero the pad columns [420,448): 4 lanes x 7 columns
    int base = KC + (lane - DEDGE - 1);
#pragma unroll
    for (int c = 0; c < KCP - KC; c += 4)
      if (base + c < KCP) row[base + c] = 0;
  }
}

// ---- MFMA GEMM: C[M,Nn] = A[M,KS](bf16) * Bt[Nn,KS](bf16)^T ; 128x128 tile, BK=32 ----
template <int KS, bool OBF>
__global__ __launch_bounds__(256) void mfma_gemm(const u16* __restrict__ A,
                                                 const u16* __restrict__ Bt,
                                                 void* __restrict__ Cout, int M, int Nn) {
  __shared__ __align__(16) u16 sA[128 * 32];
  __shared__ __align__(16) u16 sB[128 * 32];
  const int tid = threadIdx.x;
  const int w = tid >> 6, l = tid & 63;
  const int lr = l & 15, kg = l >> 4;
  const int m0 = blockIdx.y * 128, n0 = blockIdx.x * 128;
  const int wr = w >> 1, wc = w & 1;
  f32x4 acc[4][4];
  const f32x4 z4 = {0.f, 0.f, 0.f, 0.f};
#pragma unroll
  for (int i = 0; i < 4; ++i)
#pragma unroll
    for (int j = 0; j < 4; ++j) acc[i][j] = z4;

  const int ktiles = KS / 32;
  for (int kt = 0; kt < ktiles; ++kt) {
    const int k0 = kt * 32;
#pragma unroll
    for (int t = 0; t < 2; ++t) {
      int idx = w * 128 + t * 64 + l;     // 16B chunk id within A tile
      int row = idx >> 2, kp = idx & 3;
      int gm = m0 + row; gm = gm < M ? gm : M - 1;
      gload16(A + (size_t)gm * KS + k0 + kp * 8,
              (char*)sA + (size_t)(w * 128 + t * 64) * 16);
    }
#pragma unroll
    for (int t = 0; t < 2; ++t) {
      int idx = w * 128 + t * 64 + l;
      int row = idx >> 2, kp = idx & 3;
      gload16(Bt + (size_t)(n0 + row) * KS + k0 + kp * 8,
              (char*)sB + (size_t)(w * 128 + t * 64) * 16);
    }
    __syncthreads();
    bf16x8 af[4], bfr[4];
#pragma unroll
    for (int i = 0; i < 4; ++i)
      af[i] = *(const bf16x8*)(sA + (size_t)(wr * 64 + i * 16 + lr) * 32 + kg * 8);
#pragma unroll
    for (int j = 0; j < 4; ++j)
      bfr[j] = *(const bf16x8*)(sB + (size_t)(wc * 64 + j * 16 + lr) * 32 + kg * 8);
#pragma unroll
    for (int i = 0; i < 4; ++i)
#pragma unroll
      for (int j = 0; j < 4; ++j)
        acc[i][j] = __builtin_amdgcn_mfma_f32_16x16x32_bf16(af[i], bfr[j], acc[i][j], 0, 0, 0);
    __syncthreads();
  }
  // epilogue: D col = lane&15, row = (lane>>4)*4 + v  [verified C/D layout]
#pragma unroll
  for (int i = 0; i < 4; ++i) {
#pragma unroll
    for (int j = 0; j < 4; ++j) {
      int gj = n0 + wc * 64 + j * 16 + lr;
#pragma unroll
      for (int v = 0; v < 4; ++v) {
        int gm = m0 + wr * 64 + i * 16 + kg * 4 + v;
        if (gm < M) {
          if constexpr (OBF) ((u16*)Cout)[(size_t)gm * Nn + gj] = f2bf(acc[i][j][v]);
          else               ((float*)Cout)[(size_t)gm * Nn + gj] = acc[i][j][v];
        }
      }
    }
  }
}

// ---- final gather-reduce: out[n,:] = relu(edgepath(out) + b_lin + b_self + H[n,self]
//                                           + sum_e w_e * H[src_e, rel_e, :]) ----
__global__ __launch_bounds__(128) void reduceKK(const u16* __restrict__ H,
                                                const float* __restrict__ ew,
                                                const int* __restrict__ node_in,
                                                const int* __restrict__ relation,
                                                const int* __restrict__ offs,
                                                const int* __restrict__ eids,
                                                const float* __restrict__ b_lin,
                                                const float* __restrict__ b_self,
                                                float* __restrict__ out) {
  int n = blockIdx.x;
  int o0 = threadIdx.x * 4;
  float4 b1 = *(const float4*)(b_lin + o0);
  float4 b2 = *(const float4*)(b_self + o0);
  float4 oi = *(const float4*)(out + (size_t)n * DIM + o0);
  ushort4 hs = *(const ushort4*)(H + (size_t)n * NHCOL + NREL * DIM + o0);
  float a0 = oi.x + b1.x + b2.x + bf2f(hs.x);
  float a1 = oi.y + b1.y + b2.y + bf2f(hs.y);
  float a2 = oi.z + b1.z + b2.z + bf2f(hs.z);
  float a3 = oi.w + b1.w + b2.w + bf2f(hs.w);
  int p0 = offs[n], p1 = offs[n + 1];
  for (int p = p0; p < p1; ++p) {
    int e = eids[p];
    float w = ew[e];
    int src = node_in[e];
    int rel = relation[e];
    ushort4 hv = *(const ushort4*)(H + (size_t)src * NHCOL + (size_t)rel * DIM + o0);
    a0 += w * bf2f(hv.x);
    a1 += w * bf2f(hv.y);
    a2 += w * bf2f(hv.z);
    a3 += w * bf2f(hv.w);
  }
  float4 r;
  r.x = fmaxf(a0, 0.f); r.y = fmaxf(a1, 0.f);
  r.z = fmaxf(a2, 0.f); r.w = fmaxf(a3, 0.f);
  *(float4*)(out + (size_t)n * DIM + o0) = r;
}

extern "C" void kernel_launch(void* const* d_in, const int* in_sizes, int n_in,
                              void* d_out, int out_size, void* d_ws, size_t ws_size,
                              hipStream_t stream) {
  const float* node_feat = (const float*)d_in[0];
  const float* edge_weight = (const float*)d_in[1];
  const float* edge_feat = (const float*)d_in[2];
  const float* W_lin = (const float*)d_in[3];
  const float* b_lin = (const float*)d_in[4];
  const float* W_self = (const float*)d_in[5];
  const float* b_self = (const float*)d_in[6];
  const float* W_edge = (const float*)d_in[7];
  const float* b_edge = (const float*)d_in[8];
  const int* node_in = (const int*)d_in[9];
  const int* node_out = (const int*)d_in[10];
  const int* relation = (const int*)d_in[11];
  float* out = (float*)d_out;

  const int N = in_sizes[0] / DIM;
  const int E = in_sizes[1];

  char* ws = (char*)d_ws;
  size_t off = 0;
  auto take = [&](size_t b) {
    char* p = ws + off;
    off += (b + 255) & ~(size_t)255;
    return p;
  };
  u16* Abf    = (u16*)take((size_t)N * DIM * 2);
  u16* Bt     = (u16*)take((size_t)NHCOL * DIM * 2);
  u16* H      = (u16*)take((size_t)N * NHCOL * 2);
  u16* CxT    = (u16*)take((size_t)DIM * KCP * 2);
  u16* Gxb    = (u16*)take((size_t)N * KCP * 2);
  int* counts = (int*)take((size_t)N * 4);
  int* offs   = (int*)take((size_t)(N + 1) * 4);
  int* cursor = (int*)take((size_t)N * 4);
  int* eids   = (int*)take((size_t)E * 4);
  if (off > ws_size) return;  // workspace too small — fail visibly via absmax

  hipMemsetAsync(counts, 0, (size_t)N * 4, stream);

  {
    int total4 = N * DIM / 4;
    convA<<<(total4 + 255) / 256, 256, 0, stream>>>(node_feat, Abf, total4);
  }
  {
    int total4 = NHCOL * DIM / 4;
    buildBt<<<(total4 + 255) / 256, 256, 0, stream>>>(W_lin, W_self, Bt, total4);
  }
  buildCx<<<KCP, 512, 0, stream>>>(W_edge, b_edge, W_lin, CxT);
  countK<<<(E + 255) / 256, 256, 0, stream>>>(node_out, counts, E);
  scanK<<<1, 1024, 0, stream>>>(counts, offs, cursor, N);
  fillK<<<(E + 255) / 256, 256, 0, stream>>>(node_out, cursor, eids, E);

  // atomic-free edge aggregation straight to bf16 (replaces scatterG + convGx)
  gatherG<<<N, 64, 0, stream>>>(edge_feat, edge_weight, relation, offs, eids, Gxb);

  // H[N, 4096] = Abf[N,512] @ Bt[4096,512]^T  (node path + self path)
  mfma_gemm<DIM, true><<<dim3(NHCOL / 128, (N + 127) / 128), 256, 0, stream>>>(
      Abf, Bt, (void*)H, N, NHCOL);

  // edge path: out[N,512] = Gxb[N,448] @ CxT[512,448]^T
  mfma_gemm<KCP, false><<<dim3(DIM / 128, (N + 127) / 128), 256, 0, stream>>>(
      Gxb, CxT, (void*)out, N, DIM);

  // final gather-reduce + biases + relu
  reduceKK<<<N, 128, 0, stream>>>(H, edge_weight, node_in, relation, offs, eids,
                                  b_lin, b_self, out);
}

// Round 3
// 530.645 us; speedup vs baseline: 1.3945x; 1.1833x over previous
//
#include <hip/hip_runtime.h>
#include <stdint.h>

typedef unsigned short u16;
typedef __attribute__((ext_vector_type(8))) __bf16 bf16x8;
typedef __attribute__((ext_vector_type(4))) float f32x4;

#define NREL 7
#define DIM  512
#define DEDGE 59
#define KC   420     // NREL*59 + NREL (weight-sum columns)
#define KCP  448     // padded to multiple of 32
#define KTOT 4544    // NREL*512 (update) + 512 (self) + 448 (edge-G)

__device__ __forceinline__ float bf2f(u16 u) {
  union { unsigned u; float f; } c; c.u = ((unsigned)u) << 16; return c.f;
}
__device__ __forceinline__ u16 f2bf(float f) {
  union { float f; unsigned u; } c; c.f = f;
  unsigned r = ((c.u >> 16) & 1u) + 0x7FFFu;
  return (u16)((c.u + r) >> 16);
}

__device__ __forceinline__ void gload16(const void* g, void* l) {
  __builtin_amdgcn_global_load_lds(
      (__attribute__((address_space(1))) void*)g,
      (__attribute__((address_space(3))) void*)l, 16, 0, 0);
}

// ---- convert node_feat fp32 -> bf16 NF table [N,512] ----
__global__ void convA(const float* __restrict__ in, u16* __restrict__ out, int total4) {
  int i = blockIdx.x * 256 + threadIdx.x;
  if (i >= total4) return;
  float4 v = ((const float4*)in)[i];
  ushort4 r;
  r.x = f2bf(v.x); r.y = f2bf(v.y); r.z = f2bf(v.z); r.w = f2bf(v.w);
  ((ushort4*)out)[i] = r;
}

// ---- Bfull[o][k] bf16, [512][KTOT]: k<3584 -> W_lin[o][k]; 3584..4095 -> W_self[o][k-3584] ----
__global__ void buildBW(const float* __restrict__ W_lin, const float* __restrict__ W_self,
                        u16* __restrict__ Bfull, int total4) {
  int gid = blockIdx.x * 256 + threadIdx.x;
  if (gid >= total4) return;
  int idx = gid * 4;
  int o = idx >> 12;          // / 4096
  int k = idx & 4095;
  const float* src = (k < NREL * DIM) ? (W_lin + (size_t)o * (NREL * DIM) + k)
                                      : (W_self + (size_t)o * DIM + (k - NREL * DIM));
  float4 v = *(const float4*)src;
  ushort4 rr;
  rr.x = f2bf(v.x); rr.y = f2bf(v.y); rr.z = f2bf(v.z); rr.w = f2bf(v.w);
  *(ushort4*)(Bfull + (size_t)o * KTOT + k) = rr;
}

// ---- Bfull cols [4096, 4544): c=r*59+de -> sum_d W_edge[d,de]*W_lin[o,r*512+d];
//      c=413+r -> sum_d b_edge[d]*W_lin[o,r*512+d]; c>=420 -> 0 ----
__global__ __launch_bounds__(512) void buildCx(const float* __restrict__ W_edge,
                                               const float* __restrict__ b_edge,
                                               const float* __restrict__ W_lin,
                                               u16* __restrict__ Bfull) {
  int c = blockIdx.x;          // 0..447
  int o = threadIdx.x;         // 0..511
  u16* dst = Bfull + (size_t)o * KTOT + NREL * DIM + DIM;  // col base 4096
  if (c >= KC) { dst[c] = 0; return; }
  __shared__ float col[DIM];
  int r;
  if (c < NREL * DEDGE) {
    r = c / DEDGE;
    int de = c - r * DEDGE;
    col[o] = W_edge[(size_t)o * DEDGE + de];
  } else {
    r = c - NREL * DEDGE;
    col[o] = b_edge[o];
  }
  __syncthreads();
  const float* wrow = W_lin + (size_t)o * (NREL * DIM) + (size_t)r * DIM;
  float acc = 0.f;
#pragma unroll 8
  for (int d = 0; d < DIM; ++d) acc += col[d] * wrow[d];
  dst[c] = f2bf(acc);
}

// ---- two-level CSR keyed by (node_out, relation) ----
__global__ void countK2(const int* __restrict__ node_out, const int* __restrict__ relation,
                        int* __restrict__ counts2, int E) {
  int e = blockIdx.x * 256 + threadIdx.x;
  if (e < E) atomicAdd(&counts2[node_out[e] * 8 + relation[e]], 1);
}

__global__ void scanNode(const int* __restrict__ counts2, int* __restrict__ counts, int N) {
  int n = blockIdx.x * 256 + threadIdx.x;
  if (n >= N) return;
  int s = 0;
#pragma unroll
  for (int r = 0; r < NREL; ++r) s += counts2[n * 8 + r];
  counts[n] = s;
}

__global__ __launch_bounds__(1024) void scanK(const int* __restrict__ counts,
                                              int* __restrict__ offs, int n) {
  __shared__ int lds[1024];
  int tid = threadIdx.x;
  int carry = 0;
  for (int base = 0; base < n; base += 1024) {
    int i = base + tid;
    int v = (i < n) ? counts[i] : 0;
    lds[tid] = v;
    __syncthreads();
    for (int o = 1; o < 1024; o <<= 1) {
      int t = (tid >= o) ? lds[tid - o] : 0;
      __syncthreads();
      lds[tid] += t;
      __syncthreads();
    }
    int excl = lds[tid] - v;
    if (i < n) offs[i] = carry + excl;
    int total = lds[1023];
    carry += total;
    __syncthreads();
  }
  if (tid == 0) offs[n] = carry;
}

// per-node 8-slot prefix: offs2[n*8+r] = segment start; offs2[n*8+7] = node end
__global__ void offs2K(const int* __restrict__ offs, const int* __restrict__ counts2,
                       int* __restrict__ offs2, int* __restrict__ cursor2, int N) {
  int n = blockIdx.x * 256 + threadIdx.x;
  if (n >= N) return;
  int base = offs[n];
#pragma unroll
  for (int r = 0; r < NREL; ++r) {
    offs2[n * 8 + r] = base;
    cursor2[n * 8 + r] = base;
    base += counts2[n * 8 + r];
  }
  offs2[n * 8 + 7] = base;
}

__global__ void fillK2(const int* __restrict__ node_in, const int* __restrict__ node_out,
                       const int* __restrict__ relation, const float* __restrict__ ew,
                       int* __restrict__ cursor2, int* __restrict__ eids,
                       uint2* __restrict__ pairs, int E) {
  int e = blockIdx.x * 256 + threadIdx.x;
  if (e >= E) return;
  int p = atomicAdd(&cursor2[node_out[e] * 8 + relation[e]], 1);
  eids[p] = e;
  pairs[p] = make_uint2((unsigned)node_in[e], __float_as_uint(ew[e]));
}

// ---- edge-G aggregation (rel-segmented, atomic-free): Mfull cols [4096, 4544) ----
__global__ __launch_bounds__(64) void gatherG2(const float* __restrict__ ef,
                                               const int* __restrict__ eids,
                                               const uint2* __restrict__ pairs,
                                               const int* __restrict__ offs2,
                                               u16* __restrict__ Mfull) {
  int n = blockIdx.x;
  int lane = threadIdx.x;
  u16* row = Mfull + (size_t)n * KTOT + NREL * DIM + DIM;  // col 4096
  int base = n * 8;
  for (int r = 0; r < NREL; ++r) {
    int p0 = offs2[base + r], p1 = offs2[base + r + 1];
    float acc = 0.f;
    for (int p = p0; p < p1; ++p) {
      int e = __builtin_amdgcn_readfirstlane(eids[p]);
      float w = __uint_as_float(__builtin_amdgcn_readfirstlane(pairs[p].y));
      float v = (lane < DEDGE) ? ef[(size_t)e * DEDGE + lane] : 1.0f;
      acc += w * v;
    }
    if (lane < DEDGE) row[r * DEDGE + lane] = f2bf(acc);
    else if (lane == DEDGE) row[NREL * DEDGE + r] = f2bf(acc);
  }
  if (lane >= 60) {
    for (int c = KC + (lane - 60); c < KCP; c += 4) row[c] = 0;
  }
}

// ---- node-path aggregation from NF (20.5 MB, cache-hot) + self copy ----
__global__ __launch_bounds__(128) void aggK(const u16* __restrict__ NF,
                                            const uint2* __restrict__ pairs,
                                            const int* __restrict__ offs2,
                                            u16* __restrict__ Mfull) {
  int n = blockIdx.x;
  int o0 = threadIdx.x * 4;
  u16* mrow = Mfull + (size_t)n * KTOT;
  // self block: cols [3584, 4096)
  *(ushort4*)(mrow + NREL * DIM + o0) = *(const ushort4*)(NF + (size_t)n * DIM + o0);
  int base = n * 8;
  for (int r = 0; r < NREL; ++r) {
    int p0 = offs2[base + r], p1 = offs2[base + r + 1];
    float a0 = 0.f, a1 = 0.f, a2 = 0.f, a3 = 0.f;
    for (int p = p0; p < p1; ++p) {
      uint2 pr = pairs[p];
      int src = __builtin_amdgcn_readfirstlane((int)pr.x);
      float w = __uint_as_float(__builtin_amdgcn_readfirstlane(pr.y));
      ushort4 hv = *(const ushort4*)(NF + (size_t)src * DIM + o0);
      a0 += w * bf2f(hv.x);
      a1 += w * bf2f(hv.y);
      a2 += w * bf2f(hv.z);
      a3 += w * bf2f(hv.w);
    }
    ushort4 st;
    st.x = f2bf(a0); st.y = f2bf(a1); st.z = f2bf(a2); st.w = f2bf(a3);
    *(ushort4*)(mrow + r * DIM + o0) = st;
  }
}

// ---- fused MFMA GEMM: out[M,512] = relu(Mfull[M,KTOT] @ Bfull[512,KTOT]^T + b_lin + b_self) ----
__global__ __launch_bounds__(256) void gemm_br(const u16* __restrict__ A,
                                               const u16* __restrict__ Bt,
                                               const float* __restrict__ b_lin,
                                               const float* __restrict__ b_self,
                                               float* __restrict__ Cout, int M) {
  __shared__ __align__(16) u16 sA[128 * 32];
  __shared__ __align__(16) u16 sB[128 * 32];
  const int tid = threadIdx.x;
  const int w = tid >> 6, l = tid & 63;
  const int lr = l & 15, kg = l >> 4;
  const int m0 = blockIdx.y * 128, n0 = blockIdx.x * 128;
  const int wr = w >> 1, wc = w & 1;
  f32x4 acc[4][4];
  const f32x4 z4 = {0.f, 0.f, 0.f, 0.f};
#pragma unroll
  for (int i = 0; i < 4; ++i)
#pragma unroll
    for (int j = 0; j < 4; ++j) acc[i][j] = z4;

  const int ktiles = KTOT / 32;
  for (int kt = 0; kt < ktiles; ++kt) {
    const int k0 = kt * 32;
#pragma unroll
    for (int t = 0; t < 2; ++t) {
      int idx = w * 128 + t * 64 + l;     // 16B chunk id within A tile
      int row = idx >> 2, kp = idx & 3;
      int gm = m0 + row; gm = gm < M ? gm : M - 1;
      gload16(A + (size_t)gm * KTOT + k0 + kp * 8,
              (char*)sA + (size_t)(w * 128 + t * 64) * 16);
    }
#pragma unroll
    for (int t = 0; t < 2; ++t) {
      int idx = w * 128 + t * 64 + l;
      int row = idx >> 2, kp = idx & 3;
      gload16(Bt + (size_t)(n0 + row) * KTOT + k0 + kp * 8,
              (char*)sB + (size_t)(w * 128 + t * 64) * 16);
    }
    __syncthreads();
    bf16x8 af[4], bfr[4];
#pragma unroll
    for (int i = 0; i < 4; ++i)
      af[i] = *(const bf16x8*)(sA + (size_t)(wr * 64 + i * 16 + lr) * 32 + kg * 8);
#pragma unroll
    for (int j = 0; j < 4; ++j)
      bfr[j] = *(const bf16x8*)(sB + (size_t)(wc * 64 + j * 16 + lr) * 32 + kg * 8);
#pragma unroll
    for (int i = 0; i < 4; ++i)
#pragma unroll
      for (int j = 0; j < 4; ++j)
        acc[i][j] = __builtin_amdgcn_mfma_f32_16x16x32_bf16(af[i], bfr[j], acc[i][j], 0, 0, 0);
    __syncthreads();
  }
  // epilogue: D col = lane&15, row = (lane>>4)*4 + v ; fuse bias + relu
#pragma unroll
  for (int i = 0; i < 4; ++i) {
#pragma unroll
    for (int j = 0; j < 4; ++j) {
      int gj = n0 + wc * 64 + j * 16 + lr;
      float bias = b_lin[gj] + b_self[gj];
#pragma unroll
      for (int v = 0; v < 4; ++v) {
        int gm = m0 + wr * 64 + i * 16 + kg * 4 + v;
        if (gm < M)
          ((float*)Cout)[(size_t)gm * DIM + gj] = fmaxf(acc[i][j][v] + bias, 0.f);
      }
    }
  }
}

extern "C" void kernel_launch(void* const* d_in, const int* in_sizes, int n_in,
                              void* d_out, int out_size, void* d_ws, size_t ws_size,
                              hipStream_t stream) {
  const float* node_feat = (const float*)d_in[0];
  const float* edge_weight = (const float*)d_in[1];
  const float* edge_feat = (const float*)d_in[2];
  const float* W_lin = (const float*)d_in[3];
  const float* b_lin = (const float*)d_in[4];
  const float* W_self = (const float*)d_in[5];
  const float* b_self = (const float*)d_in[6];
  const float* W_edge = (const float*)d_in[7];
  const float* b_edge = (const float*)d_in[8];
  const int* node_in = (const int*)d_in[9];
  const int* node_out = (const int*)d_in[10];
  const int* relation = (const int*)d_in[11];
  float* out = (float*)d_out;

  const int N = in_sizes[0] / DIM;
  const int E = in_sizes[1];

  char* ws = (char*)d_ws;
  size_t off = 0;
  auto take = [&](size_t b) {
    char* p = ws + off;
    off += (b + 255) & ~(size_t)255;
    return p;
  };
  u16* NF      = (u16*)take((size_t)N * DIM * 2);
  u16* Bfull   = (u16*)take((size_t)DIM * KTOT * 2);
  u16* Mfull   = (u16*)take((size_t)N * KTOT * 2);
  int* counts2 = (int*)take((size_t)N * 8 * 4);
  int* counts  = (int*)take((size_t)N * 4);
  int* offs    = (int*)take((size_t)(N + 1) * 4);
  int* offs2   = (int*)take((size_t)N * 8 * 4);
  int* cursor2 = (int*)take((size_t)N * 8 * 4);
  int* eids    = (int*)take((size_t)E * 4);
  uint2* pairs = (uint2*)take((size_t)E * 8);
  if (off > ws_size) return;  // workspace too small — fail visibly via absmax

  hipMemsetAsync(counts2, 0, (size_t)N * 8 * 4, stream);

  {
    int total4 = N * DIM / 4;
    convA<<<(total4 + 255) / 256, 256, 0, stream>>>(node_feat, NF, total4);
  }
  {
    int total4 = DIM * 4096 / 4;
    buildBW<<<(total4 + 255) / 256, 256, 0, stream>>>(W_lin, W_self, Bfull, total4);
  }
  buildCx<<<KCP, 512, 0, stream>>>(W_edge, b_edge, W_lin, Bfull);

  countK2<<<(E + 255) / 256, 256, 0, stream>>>(node_out, relation, counts2, E);
  scanNode<<<(N + 255) / 256, 256, 0, stream>>>(counts2, counts, N);
  scanK<<<1, 1024, 0, stream>>>(counts, offs, N);
  offs2K<<<(N + 255) / 256, 256, 0, stream>>>(offs, counts2, offs2, cursor2, N);
  fillK2<<<(E + 255) / 256, 256, 0, stream>>>(node_in, node_out, relation, edge_weight,
                                              cursor2, eids, pairs, E);

  // edge-G into Mfull cols [4096,4544)
  gatherG2<<<N, 64, 0, stream>>>(edge_feat, eids, pairs, offs2, Mfull);
  // node-path aggregation (cols [0,3584)) + self copy (cols [3584,4096))
  aggK<<<N, 128, 0, stream>>>(NF, pairs, offs2, Mfull);

  // single fused GEMM + bias + relu
  gemm_br<<<dim3(DIM / 128, (N + 127) / 128), 256, 0, stream>>>(
      Mfull, Bfull, b_lin, b_self, out, N);
}

// Round 4
// 527.884 us; speedup vs baseline: 1.4018x; 1.0052x over previous
//
#include <hip/hip_runtime.h>
#include <stdint.h>

typedef unsigned short u16;
typedef __attribute__((ext_vector_type(8))) __bf16 bf16x8;
typedef __attribute__((ext_vector_type(4))) float f32x4;

#define NREL 7
#define DIM  512
#define DEDGE 59
#define KC   420     // NREL*59 + NREL (weight-sum columns)
#define KCP  448     // padded to multiple of 32
#define KTOT 4544    // NREL*512 (update) + 512 (self) + 448 (edge-G)

__device__ __forceinline__ float bf2f(u16 u) {
  union { unsigned u; float f; } c; c.u = ((unsigned)u) << 16; return c.f;
}
__device__ __forceinline__ u16 f2bf(float f) {
  union { float f; unsigned u; } c; c.f = f;
  unsigned r = ((c.u >> 16) & 1u) + 0x7FFFu;
  return (u16)((c.u + r) >> 16);
}

__device__ __forceinline__ void gload16(const void* g, void* l) {
  __builtin_amdgcn_global_load_lds(
      (__attribute__((address_space(1))) void*)g,
      (__attribute__((address_space(3))) void*)l, 16, 0, 0);
}

// ---- convert node_feat fp32 -> bf16 NF table [N,512] ----
__global__ void convA(const float* __restrict__ in, u16* __restrict__ out, int total4) {
  int i = blockIdx.x * 256 + threadIdx.x;
  if (i >= total4) return;
  float4 v = ((const float4*)in)[i];
  ushort4 r;
  r.x = f2bf(v.x); r.y = f2bf(v.y); r.z = f2bf(v.z); r.w = f2bf(v.w);
  ((ushort4*)out)[i] = r;
}

// ---- Bfull[o][k] bf16, [512][KTOT]: k<3584 -> W_lin[o][k]; 3584..4095 -> W_self[o][k-3584] ----
__global__ void buildBW(const float* __restrict__ W_lin, const float* __restrict__ W_self,
                        u16* __restrict__ Bfull, int total4) {
  int gid = blockIdx.x * 256 + threadIdx.x;
  if (gid >= total4) return;
  int idx = gid * 4;
  int o = idx >> 12;          // / 4096
  int k = idx & 4095;
  const float* src = (k < NREL * DIM) ? (W_lin + (size_t)o * (NREL * DIM) + k)
                                      : (W_self + (size_t)o * DIM + (k - NREL * DIM));
  float4 v = *(const float4*)src;
  ushort4 rr;
  rr.x = f2bf(v.x); rr.y = f2bf(v.y); rr.z = f2bf(v.z); rr.w = f2bf(v.w);
  *(ushort4*)(Bfull + (size_t)o * KTOT + k) = rr;
}

// ---- Bfull cols [4096, 4544): c=r*59+de -> sum_d W_edge[d,de]*W_lin[o,r*512+d];
//      c=413+r -> sum_d b_edge[d]*W_lin[o,r*512+d]; c>=420 -> 0 ----
__global__ __launch_bounds__(512) void buildCx(const float* __restrict__ W_edge,
                                               const float* __restrict__ b_edge,
                                               const float* __restrict__ W_lin,
                                               u16* __restrict__ Bfull) {
  int c = blockIdx.x;          // 0..447
  int o = threadIdx.x;         // 0..511
  u16* dst = Bfull + (size_t)o * KTOT + NREL * DIM + DIM;  // col base 4096
  if (c >= KC) { dst[c] = 0; return; }
  __shared__ float col[DIM];
  int r;
  if (c < NREL * DEDGE) {
    r = c / DEDGE;
    int de = c - r * DEDGE;
    col[o] = W_edge[(size_t)o * DEDGE + de];
  } else {
    r = c - NREL * DEDGE;
    col[o] = b_edge[o];
  }
  __syncthreads();
  const float* wrow = W_lin + (size_t)o * (NREL * DIM) + (size_t)r * DIM;
  float acc = 0.f;
#pragma unroll 8
  for (int d = 0; d < DIM; ++d) acc += col[d] * wrow[d];
  dst[c] = f2bf(acc);
}

// ---- two-level CSR keyed by (node_out, relation) ----
__global__ void countK2(const int* __restrict__ node_out, const int* __restrict__ relation,
                        int* __restrict__ counts2, int E) {
  int e = blockIdx.x * 256 + threadIdx.x;
  if (e < E) atomicAdd(&counts2[node_out[e] * 8 + relation[e]], 1);
}

__global__ void scanNode(const int* __restrict__ counts2, int* __restrict__ counts, int N) {
  int n = blockIdx.x * 256 + threadIdx.x;
  if (n >= N) return;
  int s = 0;
#pragma unroll
  for (int r = 0; r < NREL; ++r) s += counts2[n * 8 + r];
  counts[n] = s;
}

__global__ __launch_bounds__(1024) void scanK(const int* __restrict__ counts,
                                              int* __restrict__ offs, int n) {
  __shared__ int lds[1024];
  int tid = threadIdx.x;
  int carry = 0;
  for (int base = 0; base < n; base += 1024) {
    int i = base + tid;
    int v = (i < n) ? counts[i] : 0;
    lds[tid] = v;
    __syncthreads();
    for (int o = 1; o < 1024; o <<= 1) {
      int t = (tid >= o) ? lds[tid - o] : 0;
      __syncthreads();
      lds[tid] += t;
      __syncthreads();
    }
    int excl = lds[tid] - v;
    if (i < n) offs[i] = carry + excl;
    int total = lds[1023];
    carry += total;
    __syncthreads();
  }
  if (tid == 0) offs[n] = carry;
}

// per-node 8-slot prefix: offs2[n*8+r] = segment start; offs2[n*8+7] = node end
__global__ void offs2K(const int* __restrict__ offs, const int* __restrict__ counts2,
                       int* __restrict__ offs2, int* __restrict__ cursor2, int N) {
  int n = blockIdx.x * 256 + threadIdx.x;
  if (n >= N) return;
  int base = offs[n];
#pragma unroll
  for (int r = 0; r < NREL; ++r) {
    offs2[n * 8 + r] = base;
    cursor2[n * 8 + r] = base;
    base += counts2[n * 8 + r];
  }
  offs2[n * 8 + 7] = base;
}

__global__ void fillK2(const int* __restrict__ node_in, const int* __restrict__ node_out,
                       const int* __restrict__ relation, const float* __restrict__ ew,
                       int* __restrict__ cursor2, int* __restrict__ eids,
                       uint2* __restrict__ pairs, int E) {
  int e = blockIdx.x * 256 + threadIdx.x;
  if (e >= E) return;
  int p = atomicAdd(&cursor2[node_out[e] * 8 + relation[e]], 1);
  eids[p] = e;
  pairs[p] = make_uint2((unsigned)node_in[e], __float_as_uint(ew[e]));
}

// ---- edge-G aggregation (rel-segmented, atomic-free): Mfull cols [4096, 4544) ----
__global__ __launch_bounds__(64) void gatherG2(const float* __restrict__ ef,
                                               const int* __restrict__ eids,
                                               const uint2* __restrict__ pairs,
                                               const int* __restrict__ offs2,
                                               u16* __restrict__ Mfull) {
  int n = blockIdx.x;
  int lane = threadIdx.x;
  u16* row = Mfull + (size_t)n * KTOT + NREL * DIM + DIM;  // col 4096
  int base = n * 8;
  for (int r = 0; r < NREL; ++r) {
    int p0 = offs2[base + r], p1 = offs2[base + r + 1];
    float acc = 0.f;
    for (int p = p0; p < p1; ++p) {
      int e = __builtin_amdgcn_readfirstlane(eids[p]);
      float w = __uint_as_float(__builtin_amdgcn_readfirstlane(pairs[p].y));
      float v = (lane < DEDGE) ? ef[(size_t)e * DEDGE + lane] : 1.0f;
      acc += w * v;
    }
    if (lane < DEDGE) row[r * DEDGE + lane] = f2bf(acc);
    else if (lane == DEDGE) row[NREL * DEDGE + r] = f2bf(acc);
  }
  if (lane >= 60) {
    for (int c = KC + (lane - 60); c < KCP; c += 4) row[c] = 0;
  }
}

// ---- node-path aggregation from NF (20.5 MB, cache-hot) + self copy ----
__global__ __launch_bounds__(128) void aggK(const u16* __restrict__ NF,
                                            const uint2* __restrict__ pairs,
                                            const int* __restrict__ offs2,
                                            u16* __restrict__ Mfull) {
  int n = blockIdx.x;
  int o0 = threadIdx.x * 4;
  u16* mrow = Mfull + (size_t)n * KTOT;
  // self block: cols [3584, 4096)
  *(ushort4*)(mrow + NREL * DIM + o0) = *(const ushort4*)(NF + (size_t)n * DIM + o0);
  int base = n * 8;
  for (int r = 0; r < NREL; ++r) {
    int p0 = offs2[base + r], p1 = offs2[base + r + 1];
    float a0 = 0.f, a1 = 0.f, a2 = 0.f, a3 = 0.f;
    for (int p = p0; p < p1; ++p) {
      uint2 pr = pairs[p];
      int src = __builtin_amdgcn_readfirstlane((int)pr.x);
      float w = __uint_as_float(__builtin_amdgcn_readfirstlane(pr.y));
      ushort4 hv = *(const ushort4*)(NF + (size_t)src * DIM + o0);
      a0 += w * bf2f(hv.x);
      a1 += w * bf2f(hv.y);
      a2 += w * bf2f(hv.z);
      a3 += w * bf2f(hv.w);
    }
    ushort4 st;
    st.x = f2bf(a0); st.y = f2bf(a1); st.z = f2bf(a2); st.w = f2bf(a3);
    *(ushort4*)(mrow + r * DIM + o0) = st;
  }
}

// ---- fused MFMA GEMM: out[M,512] = relu(Mfull[M,KTOT] @ Bfull[512,KTOT]^T + b_lin + b_self)
//      2-phase double-buffered pipeline (prefetch next K-tile before computing current),
//      XCD panel-grouping swizzle: all 4 N-blocks of an M-panel on the same XCD. ----
__global__ __launch_bounds__(256) void gemm_br(const u16* __restrict__ A,
                                               const u16* __restrict__ Bt,
                                               const float* __restrict__ b_lin,
                                               const float* __restrict__ b_self,
                                               float* __restrict__ Cout, int M) {
  __shared__ __align__(16) u16 sA[2][128 * 32];
  __shared__ __align__(16) u16 sB[2][128 * 32];
  const int tid = threadIdx.x;
  const int w = tid >> 6, l = tid & 63;
  const int lr = l & 15, kg = l >> 4;

  // panel-grouping swizzle: dispatch i -> XCD i%8. Map so panel p's 4 column
  // blocks occupy ids {xcd, xcd+8, xcd+16, xcd+24} within a 32-id group ->
  // same XCD, consecutive slots. Bijective incl. tail (npan%8 != 0).
  const int id = blockIdx.x;
  const int npan = gridDim.x >> 2;
  const int nfull = (npan >> 3) << 3;
  int p, c;
  if (id < nfull * 4) {
    int g = id >> 5, r = id & 31;
    p = g * 8 + (r & 7);
    c = r >> 3;
  } else {
    int t = id - nfull * 4;
    p = nfull + (t >> 2);
    c = t & 3;
  }
  const int m0 = p * 128, n0 = c * 128;
  const int wr = w >> 1, wc = w & 1;
  f32x4 acc[4][4];
  const f32x4 z4 = {0.f, 0.f, 0.f, 0.f};
#pragma unroll
  for (int i = 0; i < 4; ++i)
#pragma unroll
    for (int j = 0; j < 4; ++j) acc[i][j] = z4;

  const int ktiles = KTOT / 32;

  // stage K-tile kt into buffer b
  auto stage = [&](int kt, int b) {
    const int k0 = kt * 32;
#pragma unroll
    for (int t = 0; t < 2; ++t) {
      int idx = w * 128 + t * 64 + l;     // 16B chunk id within A tile
      int row = idx >> 2, kp = idx & 3;
      int gm = m0 + row; gm = gm < M ? gm : M - 1;
      gload16(A + (size_t)gm * KTOT + k0 + kp * 8,
              (char*)sA[b] + (size_t)(w * 128 + t * 64) * 16);
    }
#pragma unroll
    for (int t = 0; t < 2; ++t) {
      int idx = w * 128 + t * 64 + l;
      int row = idx >> 2, kp = idx & 3;
      gload16(Bt + (size_t)(n0 + row) * KTOT + k0 + kp * 8,
              (char*)sB[b] + (size_t)(w * 128 + t * 64) * 16);
    }
  };

  stage(0, 0);
  __syncthreads();   // drain prologue stage

  for (int kt = 0; kt < ktiles; ++kt) {
    const int cur = kt & 1;
    if (kt + 1 < ktiles) stage(kt + 1, cur ^ 1);   // prefetch next (in flight during MFMA)
    bf16x8 af[4], bfr[4];
#pragma unroll
    for (int i = 0; i < 4; ++i)
      af[i] = *(const bf16x8*)(sA[cur] + (size_t)(wr * 64 + i * 16 + lr) * 32 + kg * 8);
#pragma unroll
    for (int j = 0; j < 4; ++j)
      bfr[j] = *(const bf16x8*)(sB[cur] + (size_t)(wc * 64 + j * 16 + lr) * 32 + kg * 8);
#pragma unroll
    for (int i = 0; i < 4; ++i)
#pragma unroll
      for (int j = 0; j < 4; ++j)
        acc[i][j] = __builtin_amdgcn_mfma_f32_16x16x32_bf16(af[i], bfr[j], acc[i][j], 0, 0, 0);
    __syncthreads();   // vmcnt(0)+lgkmcnt(0)+barrier: next buffer ready, cur reads done
  }
  // epilogue: D col = lane&15, row = (lane>>4)*4 + v ; fuse bias + relu
#pragma unroll
  for (int i = 0; i < 4; ++i) {
#pragma unroll
    for (int j = 0; j < 4; ++j) {
      int gj = n0 + wc * 64 + j * 16 + lr;
      float bias = b_lin[gj] + b_self[gj];
#pragma unroll
      for (int v = 0; v < 4; ++v) {
        int gm = m0 + wr * 64 + i * 16 + kg * 4 + v;
        if (gm < M)
          ((float*)Cout)[(size_t)gm * DIM + gj] = fmaxf(acc[i][j][v] + bias, 0.f);
      }
    }
  }
}

extern "C" void kernel_launch(void* const* d_in, const int* in_sizes, int n_in,
                              void* d_out, int out_size, void* d_ws, size_t ws_size,
                              hipStream_t stream) {
  const float* node_feat = (const float*)d_in[0];
  const float* edge_weight = (const float*)d_in[1];
  const float* edge_feat = (const float*)d_in[2];
  const float* W_lin = (const float*)d_in[3];
  const float* b_lin = (const float*)d_in[4];
  const float* W_self = (const float*)d_in[5];
  const float* b_self = (const float*)d_in[6];
  const float* W_edge = (const float*)d_in[7];
  const float* b_edge = (const float*)d_in[8];
  const int* node_in = (const int*)d_in[9];
  const int* node_out = (const int*)d_in[10];
  const int* relation = (const int*)d_in[11];
  float* out = (float*)d_out;

  const int N = in_sizes[0] / DIM;
  const int E = in_sizes[1];

  char* ws = (char*)d_ws;
  size_t off = 0;
  auto take = [&](size_t b) {
    char* p = ws + off;
    off += (b + 255) & ~(size_t)255;
    return p;
  };
  u16* NF      = (u16*)take((size_t)N * DIM * 2);
  u16* Bfull   = (u16*)take((size_t)DIM * KTOT * 2);
  u16* Mfull   = (u16*)take((size_t)N * KTOT * 2);
  int* counts2 = (int*)take((size_t)N * 8 * 4);
  int* counts  = (int*)take((size_t)N * 4);
  int* offs    = (int*)take((size_t)(N + 1) * 4);
  int* offs2   = (int*)take((size_t)N * 8 * 4);
  int* cursor2 = (int*)take((size_t)N * 8 * 4);
  int* eids    = (int*)take((size_t)E * 4);
  uint2* pairs = (uint2*)take((size_t)E * 8);
  if (off > ws_size) return;  // workspace too small — fail visibly via absmax

  hipMemsetAsync(counts2, 0, (size_t)N * 8 * 4, stream);

  {
    int total4 = N * DIM / 4;
    convA<<<(total4 + 255) / 256, 256, 0, stream>>>(node_feat, NF, total4);
  }
  {
    int total4 = DIM * 4096 / 4;
    buildBW<<<(total4 + 255) / 256, 256, 0, stream>>>(W_lin, W_self, Bfull, total4);
  }
  buildCx<<<KCP, 512, 0, stream>>>(W_edge, b_edge, W_lin, Bfull);

  countK2<<<(E + 255) / 256, 256, 0, stream>>>(node_out, relation, counts2, E);
  scanNode<<<(N + 255) / 256, 256, 0, stream>>>(counts2, counts, N);
  scanK<<<1, 1024, 0, stream>>>(counts, offs, N);
  offs2K<<<(N + 255) / 256, 256, 0, stream>>>(offs, counts2, offs2, cursor2, N);
  fillK2<<<(E + 255) / 256, 256, 0, stream>>>(node_in, node_out, relation, edge_weight,
                                              cursor2, eids, pairs, E);

  // edge-G into Mfull cols [4096,4544)
  gatherG2<<<N, 64, 0, stream>>>(edge_feat, eids, pairs, offs2, Mfull);
  // node-path aggregation (cols [0,3584)) + self copy (cols [3584,4096))
  aggK<<<N, 128, 0, stream>>>(NF, pairs, offs2, Mfull);

  // single fused GEMM + bias + relu (1-D grid, swizzled in-kernel)
  {
    int npan = (N + 127) / 128;
    gemm_br<<<npan * 4, 256, 0, stream>>>(Mfull, Bfull, b_lin, b_self, out, N);
  }
}

// Round 5
// 518.849 us; speedup vs baseline: 1.4262x; 1.0174x over previous
//
#include <hip/hip_runtime.h>
#include <stdint.h>

typedef unsigned short u16;
typedef __attribute__((ext_vector_type(8))) __bf16 bf16x8;
typedef __attribute__((ext_vector_type(4))) float f32x4;

#define NREL 7
#define DIM  512
#define DEDGE 59
#define KC   420     // NREL*59 + NREL (weight-sum columns)
#define KCP  448     // padded to multiple of 32
#define KTOT 4544    // NREL*512 (update) + 512 (self) + 448 (edge-G)

__device__ __forceinline__ float bf2f(u16 u) {
  union { unsigned u; float f; } c; c.u = ((unsigned)u) << 16; return c.f;
}
__device__ __forceinline__ u16 f2bf(float f) {
  union { float f; unsigned u; } c; c.f = f;
  unsigned r = ((c.u >> 16) & 1u) + 0x7FFFu;
  return (u16)((c.u + r) >> 16);
}

__device__ __forceinline__ void gload16(const void* g, void* l) {
  __builtin_amdgcn_global_load_lds(
      (__attribute__((address_space(1))) void*)g,
      (__attribute__((address_space(3))) void*)l, 16, 0, 0);
}

// ---- convert node_feat fp32 -> bf16 NF table [N,512] ----
__global__ void convA(const float* __restrict__ in, u16* __restrict__ out, int total4) {
  int i = blockIdx.x * 256 + threadIdx.x;
  if (i >= total4) return;
  float4 v = ((const float4*)in)[i];
  ushort4 r;
  r.x = f2bf(v.x); r.y = f2bf(v.y); r.z = f2bf(v.z); r.w = f2bf(v.w);
  ((ushort4*)out)[i] = r;
}

// ---- Bfull[o][k] bf16, [512][KTOT]: k<3584 -> W_lin[o][k]; 3584..4095 -> W_self[o][k-3584] ----
__global__ void buildBW(const float* __restrict__ W_lin, const float* __restrict__ W_self,
                        u16* __restrict__ Bfull, int total4) {
  int gid = blockIdx.x * 256 + threadIdx.x;
  if (gid >= total4) return;
  int idx = gid * 4;
  int o = idx >> 12;          // / 4096
  int k = idx & 4095;
  const float* src = (k < NREL * DIM) ? (W_lin + (size_t)o * (NREL * DIM) + k)
                                      : (W_self + (size_t)o * DIM + (k - NREL * DIM));
  float4 v = *(const float4*)src;
  ushort4 rr;
  rr.x = f2bf(v.x); rr.y = f2bf(v.y); rr.z = f2bf(v.z); rr.w = f2bf(v.w);
  *(ushort4*)(Bfull + (size_t)o * KTOT + k) = rr;
}

// ---- Bfull cols [4096, 4544): c=r*59+de -> sum_d W_edge[d,de]*W_lin[o,r*512+d];
//      c=413+r -> sum_d b_edge[d]*W_lin[o,r*512+d]; c>=420 -> 0 ----
__global__ __launch_bounds__(512) void buildCx(const float* __restrict__ W_edge,
                                               const float* __restrict__ b_edge,
                                               const float* __restrict__ W_lin,
                                               u16* __restrict__ Bfull) {
  int c = blockIdx.x;          // 0..447
  int o = threadIdx.x;         // 0..511
  u16* dst = Bfull + (size_t)o * KTOT + NREL * DIM + DIM;  // col base 4096
  if (c >= KC) { dst[c] = 0; return; }
  __shared__ float col[DIM];
  int r;
  if (c < NREL * DEDGE) {
    r = c / DEDGE;
    int de = c - r * DEDGE;
    col[o] = W_edge[(size_t)o * DEDGE + de];
  } else {
    r = c - NREL * DEDGE;
    col[o] = b_edge[o];
  }
  __syncthreads();
  const float* wrow = W_lin + (size_t)o * (NREL * DIM) + (size_t)r * DIM;
  float acc = 0.f;
#pragma unroll 8
  for (int d = 0; d < DIM; ++d) acc += col[d] * wrow[d];
  dst[c] = f2bf(acc);
}

// ---- two-level CSR keyed by (node_out, relation) ----
__global__ void countK2(const int* __restrict__ node_out, const int* __restrict__ relation,
                        int* __restrict__ counts2, int E) {
  int e = blockIdx.x * 256 + threadIdx.x;
  if (e < E) atomicAdd(&counts2[node_out[e] * 8 + relation[e]], 1);
}

__global__ void scanNode(const int* __restrict__ counts2, int* __restrict__ counts, int N) {
  int n = blockIdx.x * 256 + threadIdx.x;
  if (n >= N) return;
  int s = 0;
#pragma unroll
  for (int r = 0; r < NREL; ++r) s += counts2[n * 8 + r];
  counts[n] = s;
}

__global__ __launch_bounds__(1024) void scanK(const int* __restrict__ counts,
                                              int* __restrict__ offs, int n) {
  __shared__ int lds[1024];
  int tid = threadIdx.x;
  int carry = 0;
  for (int base = 0; base < n; base += 1024) {
    int i = base + tid;
    int v = (i < n) ? counts[i] : 0;
    lds[tid] = v;
    __syncthreads();
    for (int o = 1; o < 1024; o <<= 1) {
      int t = (tid >= o) ? lds[tid - o] : 0;
      __syncthreads();
      lds[tid] += t;
      __syncthreads();
    }
    int excl = lds[tid] - v;
    if (i < n) offs[i] = carry + excl;
    int total = lds[1023];
    carry += total;
    __syncthreads();
  }
  if (tid == 0) offs[n] = carry;
}

// per-node 8-slot prefix: offs2[n*8+r] = segment start; offs2[n*8+7] = node end
__global__ void offs2K(const int* __restrict__ offs, const int* __restrict__ counts2,
                       int* __restrict__ offs2, int* __restrict__ cursor2, int N) {
  int n = blockIdx.x * 256 + threadIdx.x;
  if (n >= N) return;
  int base = offs[n];
#pragma unroll
  for (int r = 0; r < NREL; ++r) {
    offs2[n * 8 + r] = base;
    cursor2[n * 8 + r] = base;
    base += counts2[n * 8 + r];
  }
  offs2[n * 8 + 7] = base;
}

__global__ void fillK2(const int* __restrict__ node_in, const int* __restrict__ node_out,
                       const int* __restrict__ relation, const float* __restrict__ ew,
                       int* __restrict__ cursor2, int* __restrict__ eids,
                       uint2* __restrict__ pairs, int E) {
  int e = blockIdx.x * 256 + threadIdx.x;
  if (e >= E) return;
  int p = atomicAdd(&cursor2[node_out[e] * 8 + relation[e]], 1);
  eids[p] = e;
  pairs[p] = make_uint2((unsigned)node_in[e], __float_as_uint(ew[e]));
}

// ---- edge-G aggregation (rel-segmented, atomic-free): Mfull cols [4096, 4544) ----
__global__ __launch_bounds__(64) void gatherG2(const float* __restrict__ ef,
                                               const int* __restrict__ eids,
                                               const uint2* __restrict__ pairs,
                                               const int* __restrict__ offs2,
                                               u16* __restrict__ Mfull) {
  int n = blockIdx.x;
  int lane = threadIdx.x;
  u16* row = Mfull + (size_t)n * KTOT + NREL * DIM + DIM;  // col 4096
  int base = n * 8;
  for (int r = 0; r < NREL; ++r) {
    int p0 = offs2[base + r], p1 = offs2[base + r + 1];
    float acc = 0.f;
    for (int p = p0; p < p1; ++p) {
      int e = __builtin_amdgcn_readfirstlane(eids[p]);
      float w = __uint_as_float(__builtin_amdgcn_readfirstlane(pairs[p].y));
      float v = (lane < DEDGE) ? ef[(size_t)e * DEDGE + lane] : 1.0f;
      acc += w * v;
    }
    if (lane < DEDGE) row[r * DEDGE + lane] = f2bf(acc);
    else if (lane == DEDGE) row[NREL * DEDGE + r] = f2bf(acc);
  }
  if (lane >= 60) {
    for (int c = KC + (lane - 60); c < KCP; c += 4) row[c] = 0;
  }
}

// ---- node-path aggregation from NF (20.5 MB, cache-hot) + self copy ----
__global__ __launch_bounds__(128) void aggK(const u16* __restrict__ NF,
                                            const uint2* __restrict__ pairs,
                                            const int* __restrict__ offs2,
                                            u16* __restrict__ Mfull) {
  int n = blockIdx.x;
  int o0 = threadIdx.x * 4;
  u16* mrow = Mfull + (size_t)n * KTOT;
  // self block: cols [3584, 4096)
  *(ushort4*)(mrow + NREL * DIM + o0) = *(const ushort4*)(NF + (size_t)n * DIM + o0);
  int base = n * 8;
  for (int r = 0; r < NREL; ++r) {
    int p0 = offs2[base + r], p1 = offs2[base + r + 1];
    float a0 = 0.f, a1 = 0.f, a2 = 0.f, a3 = 0.f;
    for (int p = p0; p < p1; ++p) {
      uint2 pr = pairs[p];
      int src = __builtin_amdgcn_readfirstlane((int)pr.x);
      float w = __uint_as_float(__builtin_amdgcn_readfirstlane(pr.y));
      ushort4 hv = *(const ushort4*)(NF + (size_t)src * DIM + o0);
      a0 += w * bf2f(hv.x);
      a1 += w * bf2f(hv.y);
      a2 += w * bf2f(hv.z);
      a3 += w * bf2f(hv.w);
    }
    ushort4 st;
    st.x = f2bf(a0); st.y = f2bf(a1); st.z = f2bf(a2); st.w = f2bf(a3);
    *(ushort4*)(mrow + r * DIM + o0) = st;
  }
}

// ---- fused MFMA GEMM: out[M,512] = relu(Mfull[M,KTOT] @ Bfull[512,KTOT]^T + b_lin + b_self)
//      T4 counted-vmcnt pipeline: 3 LDS buffers, stage depth 2, raw s_barrier,
//      s_waitcnt vmcnt(4) in steady state (the wait targets loads 2 K-steps old).
//      XCD panel-grouping swizzle: all 4 N-blocks of an M-panel on the same XCD. ----
__global__ __launch_bounds__(256) void gemm_br(const u16* __restrict__ A,
                                               const u16* __restrict__ Bt,
                                               const float* __restrict__ b_lin,
                                               const float* __restrict__ b_self,
                                               float* __restrict__ Cout, int M) {
  __shared__ __align__(16) u16 sA[3][128 * 32];
  __shared__ __align__(16) u16 sB[3][128 * 32];
  const int tid = threadIdx.x;
  const int w = tid >> 6, l = tid & 63;
  const int lr = l & 15, kg = l >> 4;

  // panel-grouping swizzle: dispatch i -> XCD i%8. Map so panel p's 4 column
  // blocks occupy ids {xcd, xcd+8, xcd+16, xcd+24} within a 32-id group ->
  // same XCD, consecutive slots. Bijective incl. tail (npan%8 != 0).
  const int id = blockIdx.x;
  const int npan = gridDim.x >> 2;
  const int nfull = (npan >> 3) << 3;
  int p, c;
  if (id < nfull * 4) {
    int g = id >> 5, r = id & 31;
    p = g * 8 + (r & 7);
    c = r >> 3;
  } else {
    int t = id - nfull * 4;
    p = nfull + (t >> 2);
    c = t & 3;
  }
  const int m0 = p * 128, n0 = c * 128;
  const int wr = w >> 1, wc = w & 1;
  f32x4 acc[4][4];
  const f32x4 z4 = {0.f, 0.f, 0.f, 0.f};
#pragma unroll
  for (int i = 0; i < 4; ++i)
#pragma unroll
    for (int j = 0; j < 4; ++j) acc[i][j] = z4;

  const int ktiles = KTOT / 32;   // 142

  // stage K-tile kt into buffer b: 4 global_load_lds per thread (2 A + 2 B)
  auto stage = [&](int kt, int b) {
    const int k0 = kt * 32;
#pragma unroll
    for (int t = 0; t < 2; ++t) {
      int idx = w * 128 + t * 64 + l;     // 16B chunk id within A tile
      int row = idx >> 2, kp = idx & 3;
      int gm = m0 + row; gm = gm < M ? gm : M - 1;
      gload16(A + (size_t)gm * KTOT + k0 + kp * 8,
              (char*)sA[b] + (size_t)(w * 128 + t * 64) * 16);
    }
#pragma unroll
    for (int t = 0; t < 2; ++t) {
      int idx = w * 128 + t * 64 + l;
      int row = idx >> 2, kp = idx & 3;
      gload16(Bt + (size_t)(n0 + row) * KTOT + k0 + kp * 8,
              (char*)sB[b] + (size_t)(w * 128 + t * 64) * 16);
    }
  };

  // prologue: fill depth-2 pipeline
  stage(0, 0);
  stage(1, 1);
  asm volatile("s_waitcnt vmcnt(4)" ::: "memory");   // stage(0) landed, stage(1) in flight
  __builtin_amdgcn_s_barrier();
  __builtin_amdgcn_sched_barrier(0);

  for (int kt = 0; kt < ktiles; ++kt) {
    const int cur = kt % 3;
    if (kt + 2 < ktiles) stage(kt + 2, (kt + 2) % 3);   // keep 2 tiles in flight
    bf16x8 af[4], bfr[4];
#pragma unroll
    for (int i = 0; i < 4; ++i)
      af[i] = *(const bf16x8*)(sA[cur] + (size_t)(wr * 64 + i * 16 + lr) * 32 + kg * 8);
#pragma unroll
    for (int j = 0; j < 4; ++j)
      bfr[j] = *(const bf16x8*)(sB[cur] + (size_t)(wc * 64 + j * 16 + lr) * 32 + kg * 8);
#pragma unroll
    for (int i = 0; i < 4; ++i)
#pragma unroll
      for (int j = 0; j < 4; ++j)
        acc[i][j] = __builtin_amdgcn_mfma_f32_16x16x32_bf16(af[i], bfr[j], acc[i][j], 0, 0, 0);
    // counted wait: ensure stage(kt+1) landed (oldest beyond the newest 4 retired);
    // stage(kt+2) stays in flight across the barrier. Tail: drain.
    if (kt + 2 < ktiles) {
      asm volatile("s_waitcnt vmcnt(4)" ::: "memory");
    } else {
      asm volatile("s_waitcnt vmcnt(0)" ::: "memory");
    }
    __builtin_amdgcn_s_barrier();
    __builtin_amdgcn_sched_barrier(0);
  }
  // epilogue: D col = lane&15, row = (lane>>4)*4 + v ; fuse bias + relu
#pragma unroll
  for (int i = 0; i < 4; ++i) {
#pragma unroll
    for (int j = 0; j < 4; ++j) {
      int gj = n0 + wc * 64 + j * 16 + lr;
      float bias = b_lin[gj] + b_self[gj];
#pragma unroll
      for (int v = 0; v < 4; ++v) {
        int gm = m0 + wr * 64 + i * 16 + kg * 4 + v;
        if (gm < M)
          ((float*)Cout)[(size_t)gm * DIM + gj] = fmaxf(acc[i][j][v] + bias, 0.f);
      }
    }
  }
}

extern "C" void kernel_launch(void* const* d_in, const int* in_sizes, int n_in,
                              void* d_out, int out_size, void* d_ws, size_t ws_size,
                              hipStream_t stream) {
  const float* node_feat = (const float*)d_in[0];
  const float* edge_weight = (const float*)d_in[1];
  const float* edge_feat = (const float*)d_in[2];
  const float* W_lin = (const float*)d_in[3];
  const float* b_lin = (const float*)d_in[4];
  const float* W_self = (const float*)d_in[5];
  const float* b_self = (const float*)d_in[6];
  const float* W_edge = (const float*)d_in[7];
  const float* b_edge = (const float*)d_in[8];
  const int* node_in = (const int*)d_in[9];
  const int* node_out = (const int*)d_in[10];
  const int* relation = (const int*)d_in[11];
  float* out = (float*)d_out;

  const int N = in_sizes[0] / DIM;
  const int E = in_sizes[1];

  char* ws = (char*)d_ws;
  size_t off = 0;
  auto take = [&](size_t b) {
    char* p = ws + off;
    off += (b + 255) & ~(size_t)255;
    return p;
  };
  u16* NF      = (u16*)take((size_t)N * DIM * 2);
  u16* Bfull   = (u16*)take((size_t)DIM * KTOT * 2);
  u16* Mfull   = (u16*)take((size_t)N * KTOT * 2);
  int* counts2 = (int*)take((size_t)N * 8 * 4);
  int* counts  = (int*)take((size_t)N * 4);
  int* offs    = (int*)take((size_t)(N + 1) * 4);
  int* offs2   = (int*)take((size_t)N * 8 * 4);
  int* cursor2 = (int*)take((size_t)N * 8 * 4);
  int* eids    = (int*)take((size_t)E * 4);
  uint2* pairs = (uint2*)take((size_t)E * 8);
  if (off > ws_size) return;  // workspace too small — fail visibly via absmax

  hipMemsetAsync(counts2, 0, (size_t)N * 8 * 4, stream);

  {
    int total4 = N * DIM / 4;
    convA<<<(total4 + 255) / 256, 256, 0, stream>>>(node_feat, NF, total4);
  }
  {
    int total4 = DIM * 4096 / 4;
    buildBW<<<(total4 + 255) / 256, 256, 0, stream>>>(W_lin, W_self, Bfull, total4);
  }
  buildCx<<<KCP, 512, 0, stream>>>(W_edge, b_edge, W_lin, Bfull);

  countK2<<<(E + 255) / 256, 256, 0, stream>>>(node_out, relation, counts2, E);
  scanNode<<<(N + 255) / 256, 256, 0, stream>>>(counts2, counts, N);
  scanK<<<1, 1024, 0, stream>>>(counts, offs, N);
  offs2K<<<(N + 255) / 256, 256, 0, stream>>>(offs, counts2, offs2, cursor2, N);
  fillK2<<<(E + 255) / 256, 256, 0, stream>>>(node_in, node_out, relation, edge_weight,
                                              cursor2, eids, pairs, E);

  // edge-G into Mfull cols [4096,4544)
  gatherG2<<<N, 64, 0, stream>>>(edge_feat, eids, pairs, offs2, Mfull);
  // node-path aggregation (cols [0,3584)) + self copy (cols [3584,4096))
  aggK<<<N, 128, 0, stream>>>(NF, pairs, offs2, Mfull);

  // single fused GEMM + bias + relu (1-D grid, swizzled in-kernel)
  {
    int npan = (N + 127) / 128;
    gemm_br<<<npan * 4, 256, 0, stream>>>(Mfull, Bfull, b_lin, b_self, out, N);
  }
}

// Round 6
// 516.930 us; speedup vs baseline: 1.4315x; 1.0037x over previous
//
#include <hip/hip_runtime.h>
#include <stdint.h>

typedef unsigned short u16;
typedef __attribute__((ext_vector_type(8))) __bf16 bf16x8;
typedef __attribute__((ext_vector_type(4))) float f32x4;

#define NREL 7
#define DIM  512
#define DEDGE 59
#define KC   420     // NREL*59 + NREL (weight-sum columns)
#define KCP  448     // padded to multiple of 32
#define KTOT 4544    // NREL*512 (update) + 512 (self) + 448 (edge-G)

__device__ __forceinline__ float bf2f(u16 u) {
  union { unsigned u; float f; } c; c.u = ((unsigned)u) << 16; return c.f;
}
__device__ __forceinline__ u16 f2bf(float f) {
  union { float f; unsigned u; } c; c.f = f;
  unsigned r = ((c.u >> 16) & 1u) + 0x7FFFu;
  return (u16)((c.u + r) >> 16);
}

__device__ __forceinline__ void gload16(const void* g, void* l) {
  __builtin_amdgcn_global_load_lds(
      (__attribute__((address_space(1))) void*)g,
      (__attribute__((address_space(3))) void*)l, 16, 0, 0);
}

// ---- convert node_feat fp32 -> bf16 NF table [N,512] ----
__global__ void convA(const float* __restrict__ in, u16* __restrict__ out, int total4) {
  int i = blockIdx.x * 256 + threadIdx.x;
  if (i >= total4) return;
  float4 v = ((const float4*)in)[i];
  ushort4 r;
  r.x = f2bf(v.x); r.y = f2bf(v.y); r.z = f2bf(v.z); r.w = f2bf(v.w);
  ((ushort4*)out)[i] = r;
}

// ---- Bfull[o][k] bf16, [512][KTOT]: k<3584 -> W_lin[o][k]; 3584..4095 -> W_self[o][k-3584] ----
__global__ void buildBW(const float* __restrict__ W_lin, const float* __restrict__ W_self,
                        u16* __restrict__ Bfull, int total4) {
  int gid = blockIdx.x * 256 + threadIdx.x;
  if (gid >= total4) return;
  int idx = gid * 4;
  int o = idx >> 12;          // / 4096
  int k = idx & 4095;
  const float* src = (k < NREL * DIM) ? (W_lin + (size_t)o * (NREL * DIM) + k)
                                      : (W_self + (size_t)o * DIM + (k - NREL * DIM));
  float4 v = *(const float4*)src;
  ushort4 rr;
  rr.x = f2bf(v.x); rr.y = f2bf(v.y); rr.z = f2bf(v.z); rr.w = f2bf(v.w);
  *(ushort4*)(Bfull + (size_t)o * KTOT + k) = rr;
}

// ---- Bfull cols [4096, 4544): c=r*59+de -> sum_d W_edge[d,de]*W_lin[o,r*512+d];
//      c=413+r -> sum_d b_edge[d]*W_lin[o,r*512+d]; c>=420 -> 0 ----
__global__ __launch_bounds__(512) void buildCx(const float* __restrict__ W_edge,
                                               const float* __restrict__ b_edge,
                                               const float* __restrict__ W_lin,
                                               u16* __restrict__ Bfull) {
  int c = blockIdx.x;          // 0..447
  int o = threadIdx.x;         // 0..511
  u16* dst = Bfull + (size_t)o * KTOT + NREL * DIM + DIM;  // col base 4096
  if (c >= KC) { dst[c] = 0; return; }
  __shared__ float col[DIM];
  int r;
  if (c < NREL * DEDGE) {
    r = c / DEDGE;
    int de = c - r * DEDGE;
    col[o] = W_edge[(size_t)o * DEDGE + de];
  } else {
    r = c - NREL * DEDGE;
    col[o] = b_edge[o];
  }
  __syncthreads();
  const float* wrow = W_lin + (size_t)o * (NREL * DIM) + (size_t)r * DIM;
  float acc = 0.f;
#pragma unroll 8
  for (int d = 0; d < DIM; ++d) acc += col[d] * wrow[d];
  dst[c] = f2bf(acc);
}

// ---- two-level CSR keyed by (node_out, relation) ----
__global__ void countK2(const int* __restrict__ node_out, const int* __restrict__ relation,
                        int* __restrict__ counts2, int E) {
  int e = blockIdx.x * 256 + threadIdx.x;
  if (e < E) atomicAdd(&counts2[node_out[e] * 8 + relation[e]], 1);
}

__global__ void scanNode(const int* __restrict__ counts2, int* __restrict__ counts, int N) {
  int n = blockIdx.x * 256 + threadIdx.x;
  if (n >= N) return;
  int s = 0;
#pragma unroll
  for (int r = 0; r < NREL; ++r) s += counts2[n * 8 + r];
  counts[n] = s;
}

__global__ __launch_bounds__(1024) void scanK(const int* __restrict__ counts,
                                              int* __restrict__ offs, int n) {
  __shared__ int lds[1024];
  int tid = threadIdx.x;
  int carry = 0;
  for (int base = 0; base < n; base += 1024) {
    int i = base + tid;
    int v = (i < n) ? counts[i] : 0;
    lds[tid] = v;
    __syncthreads();
    for (int o = 1; o < 1024; o <<= 1) {
      int t = (tid >= o) ? lds[tid - o] : 0;
      __syncthreads();
      lds[tid] += t;
      __syncthreads();
    }
    int excl = lds[tid] - v;
    if (i < n) offs[i] = carry + excl;
    int total = lds[1023];
    carry += total;
    __syncthreads();
  }
  if (tid == 0) offs[n] = carry;
}

// per-node 8-slot prefix: offs2[n*8+r] = segment start; offs2[n*8+7] = node end
__global__ void offs2K(const int* __restrict__ offs, const int* __restrict__ counts2,
                       int* __restrict__ offs2, int* __restrict__ cursor2, int N) {
  int n = blockIdx.x * 256 + threadIdx.x;
  if (n >= N) return;
  int base = offs[n];
#pragma unroll
  for (int r = 0; r < NREL; ++r) {
    offs2[n * 8 + r] = base;
    cursor2[n * 8 + r] = base;
    base += counts2[n * 8 + r];
  }
  offs2[n * 8 + 7] = base;
}

__global__ void fillK2(const int* __restrict__ node_in, const int* __restrict__ node_out,
                       const int* __restrict__ relation, const float* __restrict__ ew,
                       int* __restrict__ cursor2, int* __restrict__ eids,
                       uint2* __restrict__ pairs, int E) {
  int e = blockIdx.x * 256 + threadIdx.x;
  if (e >= E) return;
  int p = atomicAdd(&cursor2[node_out[e] * 8 + relation[e]], 1);
  eids[p] = e;
  pairs[p] = make_uint2((unsigned)node_in[e], __float_as_uint(ew[e]));
}

// ---- edge-G aggregation (rel-segmented, atomic-free): Mfull cols [4096, 4544) ----
__global__ __launch_bounds__(64) void gatherG2(const float* __restrict__ ef,
                                               const int* __restrict__ eids,
                                               const uint2* __restrict__ pairs,
                                               const int* __restrict__ offs2,
                                               u16* __restrict__ Mfull) {
  int n = blockIdx.x;
  int lane = threadIdx.x;
  u16* row = Mfull + (size_t)n * KTOT + NREL * DIM + DIM;  // col 4096
  int base = n * 8;
  for (int r = 0; r < NREL; ++r) {
    int p0 = offs2[base + r], p1 = offs2[base + r + 1];
    float acc = 0.f;
    for (int p = p0; p < p1; ++p) {
      int e = __builtin_amdgcn_readfirstlane(eids[p]);
      float w = __uint_as_float(__builtin_amdgcn_readfirstlane(pairs[p].y));
      float v = (lane < DEDGE) ? ef[(size_t)e * DEDGE + lane] : 1.0f;
      acc += w * v;
    }
    if (lane < DEDGE) row[r * DEDGE + lane] = f2bf(acc);
    else if (lane == DEDGE) row[NREL * DEDGE + r] = f2bf(acc);
  }
  if (lane >= 60) {
    for (int c = KC + (lane - 60); c < KCP; c += 4) row[c] = 0;
  }
}

// ---- node-path aggregation from NF (20.5 MB, cache-hot) + self copy ----
__global__ __launch_bounds__(128) void aggK(const u16* __restrict__ NF,
                                            const uint2* __restrict__ pairs,
                                            const int* __restrict__ offs2,
                                            u16* __restrict__ Mfull) {
  int n = blockIdx.x;
  int o0 = threadIdx.x * 4;
  u16* mrow = Mfull + (size_t)n * KTOT;
  // self block: cols [3584, 4096)
  *(ushort4*)(mrow + NREL * DIM + o0) = *(const ushort4*)(NF + (size_t)n * DIM + o0);
  int base = n * 8;
  for (int r = 0; r < NREL; ++r) {
    int p0 = offs2[base + r], p1 = offs2[base + r + 1];
    float a0 = 0.f, a1 = 0.f, a2 = 0.f, a3 = 0.f;
    for (int p = p0; p < p1; ++p) {
      uint2 pr = pairs[p];
      int src = __builtin_amdgcn_readfirstlane((int)pr.x);
      float w = __uint_as_float(__builtin_amdgcn_readfirstlane(pr.y));
      ushort4 hv = *(const ushort4*)(NF + (size_t)src * DIM + o0);
      a0 += w * bf2f(hv.x);
      a1 += w * bf2f(hv.y);
      a2 += w * bf2f(hv.z);
      a3 += w * bf2f(hv.w);
    }
    ushort4 st;
    st.x = f2bf(a0); st.y = f2bf(a1); st.z = f2bf(a2); st.w = f2bf(a3);
    *(ushort4*)(mrow + r * DIM + o0) = st;
  }
}

// ---- fused MFMA GEMM: out[M,512] = relu(Mfull[M,KTOT] @ Bfull[512,KTOT]^T + b_lin + b_self)
//      T2 XOR bank-swizzle: 16B-slot' = slot ^ ((row>>1)&3), applied to the GLOBAL
//      source address in stage (LDS dest stays linear per global_load_lds rules),
//      inverted on the ds_read side (lane-constant sl = kg ^ ((lr>>1)&3)).
//      3-buffer counted-vmcnt pipeline + XCD panel-grouping swizzle kept from R5. ----
__global__ __launch_bounds__(256) void gemm_br(const u16* __restrict__ A,
                                               const u16* __restrict__ Bt,
                                               const float* __restrict__ b_lin,
                                               const float* __restrict__ b_self,
                                               float* __restrict__ Cout, int M) {
  __shared__ __align__(16) u16 sA[3][128 * 32];
  __shared__ __align__(16) u16 sB[3][128 * 32];
  const int tid = threadIdx.x;
  const int w = tid >> 6, l = tid & 63;
  const int lr = l & 15, kg = l >> 4;
  const int sl = kg ^ ((lr >> 1) & 3);   // swizzled 16B-slot to read (lane-constant)

  // panel-grouping swizzle: dispatch i -> XCD i%8. Map so panel p's 4 column
  // blocks occupy ids {xcd, xcd+8, xcd+16, xcd+24} within a 32-id group ->
  // same XCD, consecutive slots. Bijective incl. tail (npan%8 != 0).
  const int id = blockIdx.x;
  const int npan = gridDim.x >> 2;
  const int nfull = (npan >> 3) << 3;
  int p, c;
  if (id < nfull * 4) {
    int g = id >> 5, r = id & 31;
    p = g * 8 + (r & 7);
    c = r >> 3;
  } else {
    int t = id - nfull * 4;
    p = nfull + (t >> 2);
    c = t & 3;
  }
  const int m0 = p * 128, n0 = c * 128;
  const int wr = w >> 1, wc = w & 1;
  f32x4 acc[4][4];
  const f32x4 z4 = {0.f, 0.f, 0.f, 0.f};
#pragma unroll
  for (int i = 0; i < 4; ++i)
#pragma unroll
    for (int j = 0; j < 4; ++j) acc[i][j] = z4;

  const int ktiles = KTOT / 32;   // 142

  // stage K-tile kt into buffer b: 4 global_load_lds per thread (2 A + 2 B).
  // LDS granule (row, kp) receives GLOBAL slot kp ^ ((row>>1)&3)  (pre-swizzle).
  auto stage = [&](int kt, int b) {
    const int k0 = kt * 32;
#pragma unroll
    for (int t = 0; t < 2; ++t) {
      int idx = w * 128 + t * 64 + l;     // 16B granule id within A tile (linear dest)
      int row = idx >> 2, kp = idx & 3;
      int s = kp ^ ((row >> 1) & 3);
      int gm = m0 + row; gm = gm < M ? gm : M - 1;
      gload16(A + (size_t)gm * KTOT + k0 + s * 8,
              (char*)sA[b] + (size_t)idx * 16);
    }
#pragma unroll
    for (int t = 0; t < 2; ++t) {
      int idx = w * 128 + t * 64 + l;
      int row = idx >> 2, kp = idx & 3;
      int s = kp ^ ((row >> 1) & 3);
      gload16(Bt + (size_t)(n0 + row) * KTOT + k0 + s * 8,
              (char*)sB[b] + (size_t)idx * 16);
    }
  };

  // prologue: fill depth-2 pipeline
  stage(0, 0);
  stage(1, 1);
  asm volatile("s_waitcnt vmcnt(4)" ::: "memory");   // stage(0) landed, stage(1) in flight
  __builtin_amdgcn_s_barrier();
  __builtin_amdgcn_sched_barrier(0);

  for (int kt = 0; kt < ktiles; ++kt) {
    const int cur = kt % 3;
    if (kt + 2 < ktiles) stage(kt + 2, (kt + 2) % 3);   // keep 2 tiles in flight
    bf16x8 af[4], bfr[4];
#pragma unroll
    for (int i = 0; i < 4; ++i)
      af[i] = *(const bf16x8*)(sA[cur] + (size_t)(wr * 64 + i * 16 + lr) * 32 + sl * 8);
#pragma unroll
    for (int j = 0; j < 4; ++j)
      bfr[j] = *(const bf16x8*)(sB[cur] + (size_t)(wc * 64 + j * 16 + lr) * 32 + sl * 8);
#pragma unroll
    for (int i = 0; i < 4; ++i)
#pragma unroll
      for (int j = 0; j < 4; ++j)
        acc[i][j] = __builtin_amdgcn_mfma_f32_16x16x32_bf16(af[i], bfr[j], acc[i][j], 0, 0, 0);
    // counted wait: ensure stage(kt+1) landed (oldest beyond the newest 4 retired);
    // stage(kt+2) stays in flight across the barrier. Tail: drain.
    if (kt + 2 < ktiles) {
      asm volatile("s_waitcnt vmcnt(4)" ::: "memory");
    } else {
      asm volatile("s_waitcnt vmcnt(0)" ::: "memory");
    }
    __builtin_amdgcn_s_barrier();
    __builtin_amdgcn_sched_barrier(0);
  }
  // epilogue: D col = lane&15, row = (lane>>4)*4 + v ; fuse bias + relu
#pragma unroll
  for (int i = 0; i < 4; ++i) {
#pragma unroll
    for (int j = 0; j < 4; ++j) {
      int gj = n0 + wc * 64 + j * 16 + lr;
      float bias = b_lin[gj] + b_self[gj];
#pragma unroll
      for (int v = 0; v < 4; ++v) {
        int gm = m0 + wr * 64 + i * 16 + kg * 4 + v;
        if (gm < M)
          ((float*)Cout)[(size_t)gm * DIM + gj] = fmaxf(acc[i][j][v] + bias, 0.f);
      }
    }
  }
}

extern "C" void kernel_launch(void* const* d_in, const int* in_sizes, int n_in,
                              void* d_out, int out_size, void* d_ws, size_t ws_size,
                              hipStream_t stream) {
  const float* node_feat = (const float*)d_in[0];
  const float* edge_weight = (const float*)d_in[1];
  const float* edge_feat = (const float*)d_in[2];
  const float* W_lin = (const float*)d_in[3];
  const float* b_lin = (const float*)d_in[4];
  const float* W_self = (const float*)d_in[5];
  const float* b_self = (const float*)d_in[6];
  const float* W_edge = (const float*)d_in[7];
  const float* b_edge = (const float*)d_in[8];
  const int* node_in = (const int*)d_in[9];
  const int* node_out = (const int*)d_in[10];
  const int* relation = (const int*)d_in[11];
  float* out = (float*)d_out;

  const int N = in_sizes[0] / DIM;
  const int E = in_sizes[1];

  char* ws = (char*)d_ws;
  size_t off = 0;
  auto take = [&](size_t b) {
    char* p = ws + off;
    off += (b + 255) & ~(size_t)255;
    return p;
  };
  u16* NF      = (u16*)take((size_t)N * DIM * 2);
  u16* Bfull   = (u16*)take((size_t)DIM * KTOT * 2);
  u16* Mfull   = (u16*)take((size_t)N * KTOT * 2);
  int* counts2 = (int*)take((size_t)N * 8 * 4);
  int* counts  = (int*)take((size_t)N * 4);
  int* offs    = (int*)take((size_t)(N + 1) * 4);
  int* offs2   = (int*)take((size_t)N * 8 * 4);
  int* cursor2 = (int*)take((size_t)N * 8 * 4);
  int* eids    = (int*)take((size_t)E * 4);
  uint2* pairs = (uint2*)take((size_t)E * 8);
  if (off > ws_size) return;  // workspace too small — fail visibly via absmax

  hipMemsetAsync(counts2, 0, (size_t)N * 8 * 4, stream);

  {
    int total4 = N * DIM / 4;
    convA<<<(total4 + 255) / 256, 256, 0, stream>>>(node_feat, NF, total4);
  }
  {
    int total4 = DIM * 4096 / 4;
    buildBW<<<(total4 + 255) / 256, 256, 0, stream>>>(W_lin, W_self, Bfull, total4);
  }
  buildCx<<<KCP, 512, 0, stream>>>(W_edge, b_edge, W_lin, Bfull);

  countK2<<<(E + 255) / 256, 256, 0, stream>>>(node_out, relation, counts2, E);
  scanNode<<<(N + 255) / 256, 256, 0, stream>>>(counts2, counts, N);
  scanK<<<1, 1024, 0, stream>>>(counts, offs, N);
  offs2K<<<(N + 255) / 256, 256, 0, stream>>>(offs, counts2, offs2, cursor2, N);
  fillK2<<<(E + 255) / 256, 256, 0, stream>>>(node_in, node_out, relation, edge_weight,
                                              cursor2, eids, pairs, E);

  // edge-G into Mfull cols [4096,4544)
  gatherG2<<<N, 64, 0, stream>>>(edge_feat, eids, pairs, offs2, Mfull);
  // node-path aggregation (cols [0,3584)) + self copy (cols [3584,4096))
  aggK<<<N, 128, 0, stream>>>(NF, pairs, offs2, Mfull);

  // single fused GEMM + bias + relu (1-D grid, swizzled in-kernel)
  {
    int npan = (N + 127) / 128;
    gemm_br<<<npan * 4, 256, 0, stream>>>(Mfull, Bfull, b_lin, b_self, out, N);
  }
}